// Round 13
// baseline (670.806 us; speedup 1.0000x reference)
//
#include <hip/hip_runtime.h>
#include <math.h>
#include <stdint.h>

#define D 128
#define MAXNORM (1.0f - 4e-3f)
#define ART_CLAMP 0.9999999f  /* fp32(1 - 1e-7) */
#define BKT_BITS 7             /* 128 nodes per bucket */
#define BKT_NODES 128
#define BKT_CAP 4096           /* LDS sort capacity; mean deg*128 = 2048, 40 sigma margin */
#define NB_ROWN 1024           /* rowNorms virtual grid (fixed) */

typedef __attribute__((ext_vector_type(8))) short short8;   // 8 bf16 (4 VGPR)
typedef __attribute__((ext_vector_type(4))) float float4v;  // MFMA C/D (4 fp32)
typedef __attribute__((ext_vector_type(4))) int intv4;      // 16B gather load

// butterfly all-reduce: every lane ends with the 64-lane total
__device__ __forceinline__ float waveAllReduce(float v) {
#pragma unroll
    for (int off = 32; off; off >>= 1) v += __shfl_xor(v, off, 64);
    return v;
}

// all-reduce across a 16-lane group (lanes differing in low 4 bits)
__device__ __forceinline__ float reduce16(float v) {
    v += __shfl_xor(v, 8, 64);
    v += __shfl_xor(v, 4, 64);
    v += __shfl_xor(v, 2, 64);
    v += __shfl_xor(v, 1, 64);
    return v;
}

// fp32 -> bf16 bits, round-to-nearest-even
__device__ __forceinline__ uint16_t f2bf(float f) {
    uint32_t u = __float_as_uint(f);
    uint32_t r = u + 0x7FFFu + ((u >> 16) & 1u);
    return (uint16_t)(r >> 16);
}
__device__ __forceinline__ float bf2f(uint16_t b) {
    return __uint_as_float((uint32_t)b << 16);
}

// ---- fast transcendentals (HW v_exp/v_log/v_rcp/v_sqrt, rel err ~1e-7) ----
__device__ __forceinline__ float rcpf(float x) { return __builtin_amdgcn_rcpf(x); }
__device__ __forceinline__ float fsqrtf(float x) { return __builtin_amdgcn_sqrtf(x); }
__device__ __forceinline__ float fast_tanh(float x) {
    float e = __expf(2.0f * x);
    float t = 1.0f - 2.0f * rcpf(e + 1.0f);
    return (x < 1e-4f) ? x : t;
}
__device__ __forceinline__ float fast_atanh(float x) {
    float t = 0.5f * __logf((1.0f + x) * rcpf(1.0f - x));
    return (x < 1e-4f) ? x : t;
}

// ---------------- LDS overlay types for fused kernels ------------------------

#define CS_STRIDE 136   /* fp32 words per LDS C-row: bank rotation, writes 2-way max */

struct GemmLds {
    short8 Ah[2][16][16];            // 8KB  A hi frags, double-buffered
    short8 Al[2][16][16];            // 8KB  A lo frags
    float Cs[16 * CS_STRIDE];        // 8.7KB C redistribution
};
struct BinLds { int cnt[1024]; int base[1024]; };
struct SortLds { int cnt[BKT_NODES]; int cur[BKT_NODES]; int2 buf[BKT_CAP]; };
union LdsBG { GemmLds g; BinLds b; };    // 25.1 KB
union LdsSG { GemmLds g; SortLds s; };   // 33.8 KB

// ---------------- device bodies ----------------------------------------------

__device__ __forceinline__ void rowNorms_body(int bid, int tid,
                                              const float* __restrict__ X,
                                              float* __restrict__ XN, int n) {
    int lane = tid & 63;
    int wv = (bid * 256 + tid) >> 6;
    const int nw = (NB_ROWN * 256) >> 6;
    for (int r = wv; r < n; r += nw) {
        float2 v = *(const float2*)(X + (size_t)r * D + lane * 2);
        float nn = sqrtf(waveAllReduce(v.x * v.x + v.y * v.y));
        if (lane == 0) XN[r] = nn;
    }
}

// histo: per-block counts -> Hcnt (coalesced, no atomics) + global bcnt with
// block-staggered atomics (kills the lockstep per-address contention bursts).
__device__ __forceinline__ void histo_body(int bid, int tid,
                                           const int* __restrict__ DST,
                                           int* __restrict__ bcnt,
                                           int* __restrict__ Hcnt, int E, int B,
                                           int* cnt) {
    for (int i = tid; i < B; i += 256) cnt[i] = 0;
    __syncthreads();
    int start = bid * 8192;
    int endE = min(start + 8192, E);
    for (int e = start + tid; e < endE; e += 256)
        atomicAdd(&cnt[DST[e] >> BKT_BITS], 1);
    __syncthreads();
    int off = (bid * 131) % B;
    for (int i = tid; i < B; i += 256) {
        int j = i + off;
        if (j >= B) j -= B;
        int c = cnt[j];
        Hcnt[bid * B + j] = c;
        if (c) atomicAdd(&bcnt[j], c);
    }
}

__device__ __forceinline__ void prepW_body(int bid, int tid,
                                           const float* __restrict__ W1,
                                           const float* __restrict__ W2,
                                           uint16_t* __restrict__ Whi1,
                                           uint16_t* __restrict__ Wlo1,
                                           uint16_t* __restrict__ Whi2,
                                           uint16_t* __restrict__ Wlo2) {
    int i = bid * 256 + tid;  // 0..16383
    float a1 = W1[i];
    uint16_t h1 = f2bf(a1);
    Whi1[i] = h1;
    Wlo1[i] = f2bf(a1 - bf2f(h1));
    float a2 = W2[i];
    uint16_t h2 = f2bf(a2);
    Whi2[i] = h2;
    Wlo2[i] = f2bf(a2 - bf2f(h2));
}

__device__ __forceinline__ void bias_body(int bid, int tid,
                                          const float* __restrict__ B1,
                                          const float* __restrict__ B2,
                                          float* __restrict__ HBOUT) {
    if (tid >= 64) return;   // one wave; no barriers in this body
    int lane = tid;
    const float* Bp = bid ? B2 : B1;
    float v0 = Bp[lane], v1 = Bp[lane + 64];
    float nn = fmaxf(sqrtf(waveAllReduce(v0 * v0 + v1 * v1)), 1e-15f);
    float t = tanhf(nn);
    float sc = t / nn;
    float pn = fmaxf(t, 1e-15f);
    if (pn > MAXNORM) sc *= MAXNORM / pn;
    HBOUT[bid * D + lane] = v0 * sc;
    HBOUT[bid * D + lane + 64] = v1 * sc;
}

// binEdges: single scatter pass; bases precomputed (Hbase), no global atomics.
__device__ __forceinline__ void binEdges_body(int bid, int tid,
                                              const int* __restrict__ DST,
                                              const int* __restrict__ SRC,
                                              const float* __restrict__ EW,
                                              const int* __restrict__ Hbase,
                                              int2* __restrict__ binned, int E, int B,
                                              int* cnt, int* base) {
    for (int i = tid; i < B; i += 256) {
        base[i] = Hbase[bid * B + i];
        cnt[i] = 0;
    }
    __syncthreads();
    int start = bid * 8192;
    int endE = min(start + 8192, E);
    for (int e = start + tid; e < endE; e += 256) {
        int d = DST[e];
        int bk = d >> BKT_BITS;
        int r = atomicAdd(&cnt[bk], 1);
        binned[base[bk] + r] =
            make_int2(SRC[e] | ((d & (BKT_NODES - 1)) << 24), __float_as_int(EW[e]));
    }
}

__device__ __forceinline__ void sort_body(int b, int tid,
                                          int2* __restrict__ binned,
                                          const int* __restrict__ boff,
                                          int* __restrict__ rp, int n,
                                          int* cnt, int* cur, int2* buf) {
    int beg = boff[b], end = boff[b + 1];
    if (tid < BKT_NODES) cnt[tid] = 0;
    __syncthreads();
    for (int e = beg + tid; e < end; e += 256)
        atomicAdd(&cnt[((uint32_t)binned[e].x) >> 24], 1);
    __syncthreads();
    // exclusive scan over 128 counters (Hillis-Steele, uniform syncs)
    int v = (tid < BKT_NODES) ? cnt[tid] : 0;
    if (tid < BKT_NODES) cur[tid] = v;
    __syncthreads();
    for (int off = 1; off < BKT_NODES; off <<= 1) {
        int t = (tid < BKT_NODES && tid >= off) ? cur[tid - off] : 0;
        __syncthreads();
        if (tid < BKT_NODES) cur[tid] += t;
        __syncthreads();
    }
    if (tid < BKT_NODES) {
        int ex = cur[tid] - v;
        int g = b * BKT_NODES + tid;
        if (g < n) rp[g] = beg + ex;
        cur[tid] = ex;   // scatter cursor
    }
    __syncthreads();
    for (int e = beg + tid; e < end; e += 256) {
        int2 pr = binned[e];
        int dl = ((uint32_t)pr.x) >> 24;
        int pos = atomicAdd(&cur[dl], 1);
        if (pos < BKT_CAP) buf[pos] = make_int2(pr.x & 0x00FFFFFF, pr.y);
    }
    __syncthreads();
    int cnt_tot = end - beg;
    for (int i = tid; i < cnt_tot && i < BKT_CAP; i += 256)
        binned[beg + i] = buf[i];
}

// ---------------- MFMA GEMM body (v4, byte-identical math) -------------------

__device__ __forceinline__ void split8(const float* v, short8* hi, short8* lo) {
    union { uint32_t u[4]; short8 s; } H, L;
#pragma unroll
    for (int i = 0; i < 4; i++) {
        uint16_t h0 = f2bf(v[2 * i]), h1 = f2bf(v[2 * i + 1]);
        uint16_t l0 = f2bf(v[2 * i] - bf2f(h0));
        uint16_t l1 = f2bf(v[2 * i + 1] - bf2f(h1));
        H.u[i] = (uint32_t)h0 | ((uint32_t)h1 << 16);
        L.u[i] = (uint32_t)l0 | ((uint32_t)l1 << 16);
    }
    *hi = H.s;
    *lo = L.s;
}

template <bool ENCODE>
__device__ __forceinline__ void gemm_body(int gbid, int rowOff, int tid,
                                          const float* __restrict__ A,
                                          const uint16_t* __restrict__ Whi,
                                          const uint16_t* __restrict__ Wlo,
                                          const float* __restrict__ XN,
                                          const float* __restrict__ HB,
                                          uint16_t* __restrict__ XT, int n,
                                          GemmLds* L) {
    int lane = tid & 63;
    int wv = tid >> 6;       // wave 0..3
    int tx = lane & 15;      // A row / B col / C col index within tile
    int q = lane >> 4;       // k-group (0..3)
    int sw = tx & 7;
    int row0 = rowOff + gbid * 64;

    // ---- W fragments in registers: ct = 2*wv + c, W row = 16*ct + tx --------
    short8 wh[2][4], wl[2][4];
#pragma unroll
    for (int c = 0; c < 2; c++) {
        int wrow = 16 * (2 * wv + c) + tx;
        const uint16_t* ph = Whi + (size_t)wrow * D + q * 8;
        const uint16_t* pl = Wlo + (size_t)wrow * D + q * 8;
#pragma unroll
        for (int t = 0; t < 4; t++) {
            wh[c][t] = *(const short8*)(ph + t * 32);
            wl[c][t] = *(const short8*)(pl + t * 32);
        }
    }

    // hb fragment (col j = 16c + tx), once per block
    float hbf[8];
#pragma unroll
    for (int c = 0; c < 8; c++) hbf[c] = HB[16 * c + tx];
    float hbsq = 0.f;
#pragma unroll
    for (int c = 0; c < 8; c++) hbsq += hbf[c] * hbf[c];
    float hb2 = reduce16(hbsq);

    // A loader: wave wv owns k-slice [32wv, 32wv+32), lane (tx,q) -> 8 floats
    auto loadA = [&](int tau, float4& v0, float4& v1) {
        int gr = row0 + tau * 16 + tx;
        if (gr >= n) gr = n - 1;  // clamp; epilogue guarded
        const float4* ap = (const float4*)(A + (size_t)gr * D + wv * 32 + q * 8);
        v0 = ap[0];
        v1 = ap[1];
    };
    auto splitStore = [&](int b, float4 v0, float4 v1) {
        float v[8] = {v0.x, v0.y, v0.z, v0.w, v1.x, v1.y, v1.z, v1.w};
        short8 hi, lo;
        split8(v, &hi, &lo);
        int pch = (4 * wv + q) ^ sw;
        L->Ah[b][tx][pch] = hi;
        L->Al[b][tx][pch] = lo;
    };

    // ---- prologue: tile 0 split into buf0; tile 1 loads in flight ----
    float4 pa0, pa1;
    loadA(0, pa0, pa1);
    splitStore(0, pa0, pa1);
    loadA(1, pa0, pa1);
    __syncthreads();

#pragma unroll
    for (int tau = 0; tau < 4; tau++) {
        int b = tau & 1;
        // ---- MFMA: 4 k-steps x 2 col-tiles x 3 products, A frags from LDS --
        float4v acc[2];
        acc[0] = (float4v){0.f, 0.f, 0.f, 0.f};
        acc[1] = (float4v){0.f, 0.f, 0.f, 0.f};
#pragma unroll
        for (int t = 0; t < 4; t++) {
            int pch = (4 * t + q) ^ sw;
            short8 ahi = L->Ah[b][tx][pch];
            short8 alo = L->Al[b][tx][pch];
#pragma unroll
            for (int c = 0; c < 2; c++) {
                acc[c] = __builtin_amdgcn_mfma_f32_16x16x32_bf16(ahi, wh[c][t], acc[c], 0, 0, 0);
                acc[c] = __builtin_amdgcn_mfma_f32_16x16x32_bf16(ahi, wl[c][t], acc[c], 0, 0, 0);
                acc[c] = __builtin_amdgcn_mfma_f32_16x16x32_bf16(alo, wh[c][t], acc[c], 0, 0, 0);
            }
        }

        // ---- scatter acc to Cs: C[lr = 4q+p][col = 16*(2wv+c)+tx] ----------
#pragma unroll
        for (int c = 0; c < 2; c++) {
            int col = 16 * (2 * wv + c) + tx;
#pragma unroll
            for (int p = 0; p < 4; p++) {
                int lr = 4 * q + p;
                L->Cs[lr * CS_STRIDE + ((col + 4 * lr) & 127)] = acc[c][p];
            }
        }

        // ---- split tile tau+1 into buf b^1; prefetch tile tau+2 ------------
        if (tau < 3) {
            splitStore(b ^ 1, pa0, pa1);
            if (tau < 2) loadA(tau + 2, pa0, pa1);
        }
        __syncthreads();   // Cs ready; A(tau+1) ready

        // ---- epilogue: 16-lane group (wv,q) owns row lr = 4*wv + q ---------
        int lr = 4 * wv + q;
        int row = row0 + tau * 16 + lr;
        if (row < n) {   // uniform within the 16-lane group
            float y[8];
#pragma unroll
            for (int c = 0; c < 8; c++)
                y[c] = L->Cs[lr * CS_STRIDE + ((16 * c + tx + 4 * lr) & 127)];

            float s = 0.f;
#pragma unroll
            for (int c = 0; c < 8; c++) s += y[c] * y[c];
            float yn2 = reduce16(s);
            float sc, xns;
            if (ENCODE) {
                float nn = fmaxf(XN[row], 1e-15f);
                float t = fast_tanh(nn);
                sc = t * rcpf(nn);                  // expmap0 scale
                float pn = fmaxf(t, 1e-15f);
                if (pn > MAXNORM) { sc *= MAXNORM * rcpf(pn); pn = MAXNORM; }  // proj
                xns = pn;
            } else {
                sc = 1.0f;
                xns = fmaxf(XN[row], 1e-15f);
            }
            float mxn2 = sc * sc * yn2;
            float mxn = fmaxf(fsqrtf(mxn2), 1e-15f);
            float arg = (mxn * rcpf(xns)) * fast_atanh(fminf(xns, ART_CLAMP));
            float t = fast_tanh(arg);
            float s2 = (mxn2 == 0.0f) ? 0.0f : (sc * t * rcpf(mxn));  // zero-row guard
            float h[8];
#pragma unroll
            for (int c = 0; c < 8; c++) h[c] = y[c] * s2;
            float rn = fmaxf(t, 1e-15f);   // ||res|| == t analytically
            float hn = rn;
            if (rn > MAXNORM) {
                float f = MAXNORM * rcpf(rn);
#pragma unroll
                for (int c = 0; c < 8; c++) h[c] *= f;
                hn = MAXNORM;
            }
            float x2 = hn * hn;
            float d0 = 0.f;
#pragma unroll
            for (int c = 0; c < 8; c++) d0 += h[c] * hbf[c];
            float xy = reduce16(d0);
            float k1 = 1.0f + 2.0f * xy + hb2;
            float k2 = 1.0f - x2;
            float den = fmaxf(1.0f + 2.0f * xy + x2 * hb2, 1e-15f);
            float rden = rcpf(den);
            float av[8];
            float s3 = 0.f;
#pragma unroll
            for (int c = 0; c < 8; c++) {
                av[c] = (k1 * h[c] + k2 * hbf[c]) * rden;
                s3 += av[c] * av[c];
            }
            float an = fmaxf(fsqrtf(reduce16(s3)), 1e-15f);
            float fproj = 1.0f;
            if (an > MAXNORM) { fproj = MAXNORM * rcpf(an); an = MAXNORM; }
            float lm = fproj * fast_atanh(fminf(an, ART_CLAMP)) * rcpf(an);  // proj+logmap0
            uint16_t* o = XT + (size_t)row * D + tx;
#pragma unroll
            for (int c = 0; c < 8; c++) o[16 * c] = f2bf(av[c] * lm);
        }
        __syncthreads();   // Cs free for next tile's scatter
    }
}

// ---------------- CSR aggregation body (4-deep pipeline + degree-perm) -------
// perm maps slot idx -> node id, sorted by DESCENDING degree. The 4 nodes in
// a wave then have near-equal degree, so the wave-max-degree padded loop
// iterations (~24% at Poisson(16), each issuing real queue-slot-consuming
// gathers) vanish. Per-node math/edge-order unchanged -> output bits
// identical. perm == nullptr -> identity (fallback).

template <bool STORE_HN>
__device__ __forceinline__ void agg_body(int gbid, int tid,
                                         const uint16_t* __restrict__ XT,
                                         const int* __restrict__ rp,
                                         const int2* __restrict__ sorted,
                                         const int* __restrict__ perm,
                                         float* __restrict__ OUT,
                                         float* __restrict__ HN, int n) {
    int lane = tid & 63;
    int q = lane >> 4;                         // node slot within wave (0..3)
    int tx = lane & 15;                        // 16-B chunk within row
    int idx = gbid * 16 + (tid >> 6) * 4 + q;  // slot id
    bool valid = (idx < n);
    int g = valid ? (perm ? perm[idx] : idx) : (n - 1);   // node id
    uint32_t beg = (uint32_t)rp[g];
    uint32_t end = valid ? (uint32_t)rp[g + 1] : beg;
    uint32_t deg = end - beg;

    // wave-max degree -> uniform trip count (≈ per-node degree after perm)
    int m = (int)deg;
    m = max(m, __shfl_xor(m, 16, 64));
    m = max(m, __shfl_xor(m, 32, 64));
    int ms = __builtin_amdgcn_readfirstlane(m);

    const char* sbase = (const char*)sorted;
    const char* xbase = (const char*)XT;
    uint32_t txoff = (uint32_t)tx * 16u;
    uint32_t jb = beg * 8u;                    // byte cursor into sorted[]
    uint32_t jendb = end * 8u;
    uint32_t jlastb = (jendb > 0u) ? (jendb - 8u) : 0u;  // safe clamp target

    float a[8];
#pragma unroll
    for (int c = 0; c < 8; c++) a[c] = 0.f;

    // prologue: 4 metas in flight
    int2 e0 = *(const int2*)(sbase + min(jb, jlastb));
    int2 e1 = *(const int2*)(sbase + min(jb + 8u, jlastb));
    int2 e2 = *(const int2*)(sbase + min(jb + 16u, jlastb));
    int2 e3 = *(const int2*)(sbase + min(jb + 24u, jlastb));
    for (int i = 0; i < ms; i += 4) {
        int2 f0 = *(const int2*)(sbase + min(jb + 32u, jlastb));
        int2 f1 = *(const int2*)(sbase + min(jb + 40u, jlastb));
        int2 f2 = *(const int2*)(sbase + min(jb + 48u, jlastb));
        int2 f3 = *(const int2*)(sbase + min(jb + 56u, jlastb));
        intv4 u0 = *(const intv4*)(xbase + ((((uint32_t)e0.x) << 8) + txoff));
        intv4 u1 = *(const intv4*)(xbase + ((((uint32_t)e1.x) << 8) + txoff));
        intv4 u2 = *(const intv4*)(xbase + ((((uint32_t)e2.x) << 8) + txoff));
        intv4 u3 = *(const intv4*)(xbase + ((((uint32_t)e3.x) << 8) + txoff));
        float w0 = (jb < jendb) ? __int_as_float(e0.y) : 0.f;
        float w1 = (jb + 8u < jendb) ? __int_as_float(e1.y) : 0.f;
        float w2 = (jb + 16u < jendb) ? __int_as_float(e2.y) : 0.f;
        float w3 = (jb + 24u < jendb) ? __int_as_float(e3.y) : 0.f;
#pragma unroll
        for (int k = 0; k < 4; k++) {
            a[2 * k]     = fmaf(__uint_as_float(((uint32_t)u0[k]) << 16), w0, a[2 * k]);
            a[2 * k + 1] = fmaf(__uint_as_float(((uint32_t)u0[k]) & 0xFFFF0000u), w0, a[2 * k + 1]);
        }
#pragma unroll
        for (int k = 0; k < 4; k++) {
            a[2 * k]     = fmaf(__uint_as_float(((uint32_t)u1[k]) << 16), w1, a[2 * k]);
            a[2 * k + 1] = fmaf(__uint_as_float(((uint32_t)u1[k]) & 0xFFFF0000u), w1, a[2 * k + 1]);
        }
#pragma unroll
        for (int k = 0; k < 4; k++) {
            a[2 * k]     = fmaf(__uint_as_float(((uint32_t)u2[k]) << 16), w2, a[2 * k]);
            a[2 * k + 1] = fmaf(__uint_as_float(((uint32_t)u2[k]) & 0xFFFF0000u), w2, a[2 * k + 1]);
        }
#pragma unroll
        for (int k = 0; k < 4; k++) {
            a[2 * k]     = fmaf(__uint_as_float(((uint32_t)u3[k]) << 16), w3, a[2 * k]);
            a[2 * k + 1] = fmaf(__uint_as_float(((uint32_t)u3[k]) & 0xFFFF0000u), w3, a[2 * k + 1]);
        }
        jb += 32u;
        e0 = f0; e1 = f1; e2 = f2; e3 = f3;
    }

    // ---- stage C inline (per 16-lane group), fast transcendentals ----
    float ss = 0.f;
#pragma unroll
    for (int c = 0; c < 8; c++) ss += a[c] * a[c];
    float nn = fmaxf(fsqrtf(reduce16(ss)), 1e-15f);
    float t = fast_tanh(nn);
    float sc = t * rcpf(nn);                 // expmap0
    float pn = fmaxf(t, 1e-15f);
    if (pn > MAXNORM) { sc *= MAXNORM * rcpf(pn); pn = MAXNORM; }  // proj
    float lm = fast_atanh(fminf(pn, ART_CLAMP)) * rcpf(pn);        // logmap0
    float r[8];
    float ss2 = 0.f;
#pragma unroll
    for (int c = 0; c < 8; c++) {
        r[c] = fmaxf(lm * sc * a[c], 0.f);   // relu in tangent space
        ss2 += r[c] * r[c];
    }
    float rn = fmaxf(fsqrtf(reduce16(ss2)), 1e-15f);
    float t2 = fast_tanh(rn);
    float sc2 = t2 * rcpf(rn);               // expmap0 at c_out
    float on = fmaxf(t2, 1e-15f);
    if (on > MAXNORM) { sc2 *= MAXNORM * rcpf(on); on = MAXNORM; }
    if (valid) {
        float4* o = (float4*)(OUT + (size_t)g * D + tx * 8);
        o[0] = make_float4(r[0] * sc2, r[1] * sc2, r[2] * sc2, r[3] * sc2);
        o[1] = make_float4(r[4] * sc2, r[5] * sc2, r[6] * sc2, r[7] * sc2);
        if (STORE_HN && tx == 0) HN[g] = on;   // next layer's _norm(x)
    }
}

// ---------------- kernels ----------------------------------------------------

// fusedPre: rowNorms | bucketHisto | prepW | bias (all independent)
__global__ __launch_bounds__(256) void fusedPre(
    const float* __restrict__ X, float* __restrict__ XN, int n,
    const int* __restrict__ DST, int* __restrict__ bcnt, int* __restrict__ Hcnt,
    int E, int B, int gH,
    const float* __restrict__ W1, const float* __restrict__ W2,
    uint16_t* __restrict__ Whi1, uint16_t* __restrict__ Wlo1,
    uint16_t* __restrict__ Whi2, uint16_t* __restrict__ Wlo2,
    const float* __restrict__ B1, const float* __restrict__ B2,
    float* __restrict__ HBOUT) {
    __shared__ int cnt[1024];
    int bid = blockIdx.x, tid = threadIdx.x;
    if (bid < NB_ROWN) {
        rowNorms_body(bid, tid, X, XN, n);
    } else if (bid < NB_ROWN + gH) {
        histo_body(bid - NB_ROWN, tid, DST, bcnt, Hcnt, E, B, cnt);
    } else if (bid < NB_ROWN + gH + 64) {
        prepW_body(bid - NB_ROWN - gH, tid, W1, W2, Whi1, Wlo1, Whi2, Wlo2);
    } else {
        bias_body(bid - NB_ROWN - gH - 64, tid, B1, B2, HBOUT);
    }
}

// single block: exclusive scan of bcnt (B <= 1024) -> boff; rp[n]=boff[B]=E
__global__ __launch_bounds__(1024) void bucketScan(const int* __restrict__ bcnt,
                                                   int* __restrict__ boff,
                                                   int* __restrict__ rp_last,
                                                   int B, int E) {
    __shared__ int sd[1024];
    int tid = threadIdx.x;
    int v = (tid < B) ? bcnt[tid] : 0;
    sd[tid] = v;
    __syncthreads();
    for (int off = 1; off < 1024; off <<= 1) {
        int t = (tid >= off) ? sd[tid - off] : 0;
        __syncthreads();
        sd[tid] += t;
        __syncthreads();
    }
    int ex = sd[tid] - v;
    if (tid < B) boff[tid] = ex;
    if (tid == 0) { boff[B] = E; *rp_last = E; }
}

// scanA v2: one block per bucket; PARALLEL prefix over histo-blocks k.
__global__ __launch_bounds__(256) void scanA(const int* __restrict__ boff,
                                             const int* __restrict__ Hcnt,
                                             int* __restrict__ Hbase, int B, int gH) {
    __shared__ int sd[256];
    int b = blockIdx.x;
    int k = threadIdx.x;
    int base0 = boff[b];
    int carry = 0;
    for (int k0 = 0; k0 < gH; k0 += 256) {
        int kk = k0 + k;
        int v = (kk < gH) ? Hcnt[(size_t)kk * B + b] : 0;
        sd[k] = v;
        __syncthreads();
        for (int off = 1; off < 256; off <<= 1) {
            int t = (k >= off) ? sd[k - off] : 0;
            __syncthreads();
            sd[k] += t;
            __syncthreads();
        }
        if (kk < gH) Hbase[(size_t)kk * B + b] = base0 + carry + sd[k] - v;
        carry += sd[255];
        __syncthreads();
    }
}

// fusedBinGemm: binEdges | gemm1 blocks [0, GA)
__global__ __launch_bounds__(256, 3) void fusedBinGemm(
    const int* __restrict__ DST, const int* __restrict__ SRC,
    const float* __restrict__ EW, const int* __restrict__ Hbase,
    int2* __restrict__ binned, int E, int B, int gBin,
    const float* __restrict__ A, const uint16_t* __restrict__ Whi,
    const uint16_t* __restrict__ Wlo, const float* __restrict__ XN,
    const float* __restrict__ HB, uint16_t* __restrict__ XT, int n) {
    __shared__ LdsBG u;
    int bid = blockIdx.x, tid = threadIdx.x;
    if (bid < gBin)
        binEdges_body(bid, tid, DST, SRC, EW, Hbase, binned, E, B, u.b.cnt, u.b.base);
    else
        gemm_body<true>(bid - gBin, 0, tid, A, Whi, Wlo, XN, HB, XT, n, &u.g);
}

// fusedSortGemm: perBucketSort | gemm1 blocks [GA, gG)
__global__ __launch_bounds__(256, 3) void fusedSortGemm(
    int2* __restrict__ binned, const int* __restrict__ boff,
    int* __restrict__ rp, int n, int gSort,
    const float* __restrict__ A, const uint16_t* __restrict__ Whi,
    const uint16_t* __restrict__ Wlo, const float* __restrict__ XN,
    const float* __restrict__ HB, uint16_t* __restrict__ XT, int rowOff) {
    __shared__ LdsSG u;
    int bid = blockIdx.x, tid = threadIdx.x;
    if (bid < gSort)
        sort_body(bid, tid, binned, boff, rp, n, u.s.cnt, u.s.cur, u.s.buf);
    else
        gemm_body<true>(bid - gSort, rowOff, tid, A, Whi, Wlo, XN, HB, XT, n, &u.g);
}

// standalone gemm (layer 2)
template <bool ENCODE>
__global__ __launch_bounds__(256, 3) void gemmM(const float* __restrict__ A,
                                                const uint16_t* __restrict__ Whi,
                                                const uint16_t* __restrict__ Wlo,
                                                const float* __restrict__ XN,
                                                const float* __restrict__ HB,
                                                uint16_t* __restrict__ XT, int n) {
    __shared__ GemmLds L;
    gemm_body<ENCODE>(blockIdx.x, 0, threadIdx.x, A, Whi, Wlo, XN, HB, XT, n, &L);
}

// standalone aggregation (degree-permuted)
template <bool STORE_HN>
__global__ __launch_bounds__(256) void aggC(const uint16_t* __restrict__ XT,
                                            const int* __restrict__ rp,
                                            const int2* __restrict__ sorted,
                                            const int* __restrict__ perm,
                                            float* __restrict__ OUT,
                                            float* __restrict__ HN, int n) {
    agg_body<STORE_HN>(blockIdx.x, threadIdx.x, XT, rp, sorted, perm, OUT, HN, n);
}

// ---------------- degree-sort permutation (256-bin counting sort) ------------
// bin = 255 - min(deg,255): ascending scan => DESCENDING degree order
// (high-degree blocks launch first for better dispatch-tail balance).

__global__ __launch_bounds__(256) void degHisto(const int* __restrict__ rp,
                                                int* __restrict__ dhist, int n) {
    __shared__ int h[256];
    int tid = threadIdx.x;
    h[tid] = 0;
    __syncthreads();
    int g = blockIdx.x * 256 + tid;
    if (g < n) {
        int d = rp[g + 1] - rp[g];
        atomicAdd(&h[255 - min(d, 255)], 1);
    }
    __syncthreads();
    if (h[tid]) atomicAdd(&dhist[tid], h[tid]);
}

__global__ __launch_bounds__(256) void degScan(const int* __restrict__ dhist,
                                               int* __restrict__ dcur) {
    __shared__ int sd[256];
    int tid = threadIdx.x;
    int v = dhist[tid];
    sd[tid] = v;
    __syncthreads();
    for (int off = 1; off < 256; off <<= 1) {
        int t = (tid >= off) ? sd[tid - off] : 0;
        __syncthreads();
        sd[tid] += t;
        __syncthreads();
    }
    dcur[tid] = sd[tid] - v;   // exclusive
}

__global__ __launch_bounds__(256) void permScatter(const int* __restrict__ rp,
                                                   int* __restrict__ dcur,
                                                   int* __restrict__ perm, int n) {
    int g = blockIdx.x * 256 + threadIdx.x;
    if (g >= n) return;
    int d = rp[g + 1] - rp[g];
    int pos = atomicAdd(&dcur[255 - min(d, 255)], 1);
    perm[pos] = g;
}

// ---------------- launcher ---------------------------------------------------

extern "C" void kernel_launch(void* const* d_in, const int* in_sizes, int n_in,
                              void* d_out, int out_size, void* d_ws, size_t ws_size,
                              hipStream_t stream) {
    const float* x  = (const float*)d_in[0];
    const int*   ei = (const int*)d_in[1];
    const float* ew = (const float*)d_in[2];
    const float* w1 = (const float*)d_in[3];
    const float* b1 = (const float*)d_in[4];
    const float* w2 = (const float*)d_in[5];
    const float* b2 = (const float*)d_in[6];
    int n = in_sizes[0] / D;
    int E = in_sizes[2];
    int B = (n + BKT_NODES - 1) >> BKT_BITS;    // 782 for n=100000 (<= 1024)

    // workspace layout
    uint16_t* xtb = (uint16_t*)d_ws;               // n*D bf16 (T1 then T2, in place)
    int*   bcnt = (int*)(xtb + (size_t)n * D);     // 1024
    int*   boff = bcnt + 1024;                     // 1025
    int*   gcur = boff + 1025;                     // 1024 (unused, layout keep)
    int*   rp   = gcur + 1024;                     // n+1
    float* xn   = (float*)(rp + n + 1);            // n (X norms, then H norms)
    uint16_t* whi1 = (uint16_t*)(((uintptr_t)(xn + n) + 15) & ~(uintptr_t)15);  // 16B-aligned
    uint16_t* wlo1 = whi1 + 128 * 128;
    uint16_t* whi2 = wlo1 + 128 * 128;
    uint16_t* wlo2 = whi2 + 128 * 128;
    float* hb = (float*)(wlo2 + 128 * 128);        // 2*D
    uintptr_t p = (uintptr_t)(hb + 2 * D);
    int2* binned = (int2*)((p + 15) & ~(uintptr_t)15);  // E pairs (binned, then CSR-sorted)
    float* Hd = (float*)d_out;                     // H1 scratch + final out

    const int* dst = ei;      // edge_index[0] = segment ids (destinations)
    const int* src = ei + E;  // edge_index[1] = gather sources

    const int gE8 = (E + 8191) / 8192;
    int* Hcnt  = (int*)(binned + E);               // gE8 * B
    int* Hbase = Hcnt + (size_t)gE8 * B;           // gE8 * B
    int* dhist = Hbase + (size_t)gE8 * B;          // 256
    int* dcur  = dhist + 256;                      // 256
    int* perm  = dcur + 256;                       // n
    size_t need = (size_t)((char*)(perm + n) - (char*)d_ws);
    const int* permUse = (ws_size >= need) ? perm : nullptr;

    const int gG = (n + 63) / 64;      // gemm blocks (64 rows each, 4 tiles)
    const int GA = min(256, gG);       // gemm1 part A (overlaps binEdges)
    const int GB = gG - GA;            // gemm1 part B (overlaps perBucketSort)
    const int gAgg = (n + 15) / 16;    // 4 nodes per wave, 4 waves per block
    const int gN256 = (n + 255) / 256;

    hipMemsetAsync(bcnt, 0, 1024 * sizeof(int), stream);
    if (permUse) hipMemsetAsync(dhist, 0, 256 * sizeof(int), stream);

    // 1: rowNorms | bucketHisto(+Hcnt) | prepW | bias (independent)
    fusedPre<<<NB_ROWN + gE8 + 64 + 2, 256, 0, stream>>>(
        x, xn, n, dst, bcnt, Hcnt, E, B, gE8,
        w1, w2, whi1, wlo1, whi2, wlo2, b1, b2, hb);

    // 2: bucket scan (tiny)
    bucketScan<<<1, 1024, 0, stream>>>(bcnt, boff, rp + n, B, E);

    // 3: per-(block,bucket) base table -- PARALLEL prefix (one block/bucket)
    scanA<<<B, 256, 0, stream>>>(boff, Hcnt, Hbase, B, gE8);

    // 4: binEdges | gemm1[0, GA)
    fusedBinGemm<<<gE8 + GA, 256, 0, stream>>>(
        dst, src, ew, Hbase, binned, E, B, gE8,
        x, whi1, wlo1, xn, hb, xtb, n);

    // 5: perBucketSort | gemm1[GA, gG)
    fusedSortGemm<<<B + GB, 256, 0, stream>>>(
        binned, boff, rp, n, B,
        x, whi1, wlo1, xn, hb, xtb, GA * 64);

    // 6: degree-sort permutation (needs rp; ~5us total)
    if (permUse) {
        degHisto<<<gN256, 256, 0, stream>>>(rp, dhist, n);
        degScan<<<1, 256, 0, stream>>>(dhist, dcur);
        permScatter<<<gN256, 256, 0, stream>>>(rp, dcur, perm, n);
    }

    // 7-9: layer-1 aggregation, layer-2 gemm + aggregation (round-10 schedule)
    aggC<true><<<gAgg, 256, 0, stream>>>(xtb, rp, binned, permUse, Hd, xn, n);
    gemmM<false><<<gG, 256, 0, stream>>>(Hd, whi2, wlo2, xn, hb + D, xtb, n);
    aggC<false><<<gAgg, 256, 0, stream>>>(xtb, rp, binned, permUse,
                                          (float*)d_out, nullptr, n);
}

// Round 14
// 394.699 us; speedup vs baseline: 1.6995x; 1.6995x over previous
//
#include <hip/hip_runtime.h>
#include <math.h>
#include <stdint.h>

#define D 128
#define MAXNORM (1.0f - 4e-3f)
#define ART_CLAMP 0.9999999f  /* fp32(1 - 1e-7) */
#define BKT_BITS 7             /* 128 nodes per bucket */
#define BKT_NODES 128
#define BKT_CAP 4096           /* LDS sort capacity; mean deg*128 = 2048, 40 sigma margin */
#define NB_ROWN 1024           /* rowNorms virtual grid (fixed) */

typedef __attribute__((ext_vector_type(8))) short short8;   // 8 bf16 (4 VGPR)
typedef __attribute__((ext_vector_type(4))) float float4v;  // MFMA C/D (4 fp32)
typedef __attribute__((ext_vector_type(4))) int intv4;      // 16B gather load

// butterfly all-reduce: every lane ends with the 64-lane total
__device__ __forceinline__ float waveAllReduce(float v) {
#pragma unroll
    for (int off = 32; off; off >>= 1) v += __shfl_xor(v, off, 64);
    return v;
}

// all-reduce across a 16-lane group (lanes differing in low 4 bits)
__device__ __forceinline__ float reduce16(float v) {
    v += __shfl_xor(v, 8, 64);
    v += __shfl_xor(v, 4, 64);
    v += __shfl_xor(v, 2, 64);
    v += __shfl_xor(v, 1, 64);
    return v;
}

// fp32 -> bf16 bits, round-to-nearest-even
__device__ __forceinline__ uint16_t f2bf(float f) {
    uint32_t u = __float_as_uint(f);
    uint32_t r = u + 0x7FFFu + ((u >> 16) & 1u);
    return (uint16_t)(r >> 16);
}
__device__ __forceinline__ float bf2f(uint16_t b) {
    return __uint_as_float((uint32_t)b << 16);
}

// ---- fast transcendentals (HW v_exp/v_log/v_rcp/v_sqrt, rel err ~1e-7) ----
__device__ __forceinline__ float rcpf(float x) { return __builtin_amdgcn_rcpf(x); }
__device__ __forceinline__ float fsqrtf(float x) { return __builtin_amdgcn_sqrtf(x); }
__device__ __forceinline__ float fast_tanh(float x) {
    float e = __expf(2.0f * x);
    float t = 1.0f - 2.0f * rcpf(e + 1.0f);
    return (x < 1e-4f) ? x : t;
}
__device__ __forceinline__ float fast_atanh(float x) {
    float t = 0.5f * __logf((1.0f + x) * rcpf(1.0f - x));
    return (x < 1e-4f) ? x : t;
}

// ---------------- LDS overlay types for fused kernels ------------------------

#define CS_STRIDE 136   /* fp32 words per LDS C-row: bank rotation, writes 2-way max */

struct GemmLds {
    short8 Ah[2][16][16];            // 8KB  A hi frags, double-buffered
    short8 Al[2][16][16];            // 8KB  A lo frags
    float Cs[16 * CS_STRIDE];        // 8.7KB C redistribution
};
struct BinLds { int cnt[1024]; int base[1024]; };
struct SortLds { int cnt[BKT_NODES]; int cur[BKT_NODES]; int2 buf[BKT_CAP]; };
union LdsBG { GemmLds g; BinLds b; };    // 25.1 KB
union LdsSG { GemmLds g; SortLds s; };   // 33.8 KB

// ---------------- device bodies ----------------------------------------------

__device__ __forceinline__ void rowNorms_body(int bid, int tid,
                                              const float* __restrict__ X,
                                              float* __restrict__ XN, int n) {
    int lane = tid & 63;
    int wv = (bid * 256 + tid) >> 6;
    const int nw = (NB_ROWN * 256) >> 6;
    for (int r = wv; r < n; r += nw) {
        float2 v = *(const float2*)(X + (size_t)r * D + lane * 2);
        float nn = sqrtf(waveAllReduce(v.x * v.x + v.y * v.y));
        if (lane == 0) XN[r] = nn;
    }
}

// histo: per-block counts -> Hcnt (coalesced, no atomics) + global bcnt with
// block-staggered atomics (kills the lockstep per-address contention bursts).
__device__ __forceinline__ void histo_body(int bid, int tid,
                                           const int* __restrict__ DST,
                                           int* __restrict__ bcnt,
                                           int* __restrict__ Hcnt, int E, int B,
                                           int* cnt) {
    for (int i = tid; i < B; i += 256) cnt[i] = 0;
    __syncthreads();
    int start = bid * 8192;
    int endE = min(start + 8192, E);
    for (int e = start + tid; e < endE; e += 256)
        atomicAdd(&cnt[DST[e] >> BKT_BITS], 1);
    __syncthreads();
    int off = (bid * 131) % B;
    for (int i = tid; i < B; i += 256) {
        int j = i + off;
        if (j >= B) j -= B;
        int c = cnt[j];
        Hcnt[bid * B + j] = c;
        if (c) atomicAdd(&bcnt[j], c);
    }
}

__device__ __forceinline__ void prepW_body(int bid, int tid,
                                           const float* __restrict__ W1,
                                           const float* __restrict__ W2,
                                           uint16_t* __restrict__ Whi1,
                                           uint16_t* __restrict__ Wlo1,
                                           uint16_t* __restrict__ Whi2,
                                           uint16_t* __restrict__ Wlo2) {
    int i = bid * 256 + tid;  // 0..16383
    float a1 = W1[i];
    uint16_t h1 = f2bf(a1);
    Whi1[i] = h1;
    Wlo1[i] = f2bf(a1 - bf2f(h1));
    float a2 = W2[i];
    uint16_t h2 = f2bf(a2);
    Whi2[i] = h2;
    Wlo2[i] = f2bf(a2 - bf2f(h2));
}

__device__ __forceinline__ void bias_body(int bid, int tid,
                                          const float* __restrict__ B1,
                                          const float* __restrict__ B2,
                                          float* __restrict__ HBOUT) {
    if (tid >= 64) return;   // one wave; no barriers in this body
    int lane = tid;
    const float* Bp = bid ? B2 : B1;
    float v0 = Bp[lane], v1 = Bp[lane + 64];
    float nn = fmaxf(sqrtf(waveAllReduce(v0 * v0 + v1 * v1)), 1e-15f);
    float t = tanhf(nn);
    float sc = t / nn;
    float pn = fmaxf(t, 1e-15f);
    if (pn > MAXNORM) sc *= MAXNORM / pn;
    HBOUT[bid * D + lane] = v0 * sc;
    HBOUT[bid * D + lane + 64] = v1 * sc;
}

// binEdges: single scatter pass; bases precomputed (Hbase), no global atomics.
__device__ __forceinline__ void binEdges_body(int bid, int tid,
                                              const int* __restrict__ DST,
                                              const int* __restrict__ SRC,
                                              const float* __restrict__ EW,
                                              const int* __restrict__ Hbase,
                                              int2* __restrict__ binned, int E, int B,
                                              int* cnt, int* base) {
    for (int i = tid; i < B; i += 256) {
        base[i] = Hbase[bid * B + i];
        cnt[i] = 0;
    }
    __syncthreads();
    int start = bid * 8192;
    int endE = min(start + 8192, E);
    for (int e = start + tid; e < endE; e += 256) {
        int d = DST[e];
        int bk = d >> BKT_BITS;
        int r = atomicAdd(&cnt[bk], 1);
        binned[base[bk] + r] =
            make_int2(SRC[e] | ((d & (BKT_NODES - 1)) << 24), __float_as_int(EW[e]));
    }
}

__device__ __forceinline__ void sort_body(int b, int tid,
                                          int2* __restrict__ binned,
                                          const int* __restrict__ boff,
                                          int* __restrict__ rp, int n,
                                          int* cnt, int* cur, int2* buf) {
    int beg = boff[b], end = boff[b + 1];
    if (tid < BKT_NODES) cnt[tid] = 0;
    __syncthreads();
    for (int e = beg + tid; e < end; e += 256)
        atomicAdd(&cnt[((uint32_t)binned[e].x) >> 24], 1);
    __syncthreads();
    // exclusive scan over 128 counters (Hillis-Steele, uniform syncs)
    int v = (tid < BKT_NODES) ? cnt[tid] : 0;
    if (tid < BKT_NODES) cur[tid] = v;
    __syncthreads();
    for (int off = 1; off < BKT_NODES; off <<= 1) {
        int t = (tid < BKT_NODES && tid >= off) ? cur[tid - off] : 0;
        __syncthreads();
        if (tid < BKT_NODES) cur[tid] += t;
        __syncthreads();
    }
    if (tid < BKT_NODES) {
        int ex = cur[tid] - v;
        int g = b * BKT_NODES + tid;
        if (g < n) rp[g] = beg + ex;
        cur[tid] = ex;   // scatter cursor
    }
    __syncthreads();
    for (int e = beg + tid; e < end; e += 256) {
        int2 pr = binned[e];
        int dl = ((uint32_t)pr.x) >> 24;
        int pos = atomicAdd(&cur[dl], 1);
        if (pos < BKT_CAP) buf[pos] = make_int2(pr.x & 0x00FFFFFF, pr.y);
    }
    __syncthreads();
    int cnt_tot = end - beg;
    for (int i = tid; i < cnt_tot && i < BKT_CAP; i += 256)
        binned[beg + i] = buf[i];
}

// ---------------- MFMA GEMM body (v4, byte-identical math) -------------------

__device__ __forceinline__ void split8(const float* v, short8* hi, short8* lo) {
    union { uint32_t u[4]; short8 s; } H, L;
#pragma unroll
    for (int i = 0; i < 4; i++) {
        uint16_t h0 = f2bf(v[2 * i]), h1 = f2bf(v[2 * i + 1]);
        uint16_t l0 = f2bf(v[2 * i] - bf2f(h0));
        uint16_t l1 = f2bf(v[2 * i + 1] - bf2f(h1));
        H.u[i] = (uint32_t)h0 | ((uint32_t)h1 << 16);
        L.u[i] = (uint32_t)l0 | ((uint32_t)l1 << 16);
    }
    *hi = H.s;
    *lo = L.s;
}

template <bool ENCODE>
__device__ __forceinline__ void gemm_body(int gbid, int rowOff, int tid,
                                          const float* __restrict__ A,
                                          const uint16_t* __restrict__ Whi,
                                          const uint16_t* __restrict__ Wlo,
                                          const float* __restrict__ XN,
                                          const float* __restrict__ HB,
                                          uint16_t* __restrict__ XT, int n,
                                          GemmLds* L) {
    int lane = tid & 63;
    int wv = tid >> 6;       // wave 0..3
    int tx = lane & 15;      // A row / B col / C col index within tile
    int q = lane >> 4;       // k-group (0..3)
    int sw = tx & 7;
    int row0 = rowOff + gbid * 64;

    // ---- W fragments in registers: ct = 2*wv + c, W row = 16*ct + tx --------
    short8 wh[2][4], wl[2][4];
#pragma unroll
    for (int c = 0; c < 2; c++) {
        int wrow = 16 * (2 * wv + c) + tx;
        const uint16_t* ph = Whi + (size_t)wrow * D + q * 8;
        const uint16_t* pl = Wlo + (size_t)wrow * D + q * 8;
#pragma unroll
        for (int t = 0; t < 4; t++) {
            wh[c][t] = *(const short8*)(ph + t * 32);
            wl[c][t] = *(const short8*)(pl + t * 32);
        }
    }

    // hb fragment (col j = 16c + tx), once per block
    float hbf[8];
#pragma unroll
    for (int c = 0; c < 8; c++) hbf[c] = HB[16 * c + tx];
    float hbsq = 0.f;
#pragma unroll
    for (int c = 0; c < 8; c++) hbsq += hbf[c] * hbf[c];
    float hb2 = reduce16(hbsq);

    // A loader: wave wv owns k-slice [32wv, 32wv+32), lane (tx,q) -> 8 floats
    auto loadA = [&](int tau, float4& v0, float4& v1) {
        int gr = row0 + tau * 16 + tx;
        if (gr >= n) gr = n - 1;  // clamp; epilogue guarded
        const float4* ap = (const float4*)(A + (size_t)gr * D + wv * 32 + q * 8);
        v0 = ap[0];
        v1 = ap[1];
    };
    auto splitStore = [&](int b, float4 v0, float4 v1) {
        float v[8] = {v0.x, v0.y, v0.z, v0.w, v1.x, v1.y, v1.z, v1.w};
        short8 hi, lo;
        split8(v, &hi, &lo);
        int pch = (4 * wv + q) ^ sw;
        L->Ah[b][tx][pch] = hi;
        L->Al[b][tx][pch] = lo;
    };

    // ---- prologue: tile 0 split into buf0; tile 1 loads in flight ----
    float4 pa0, pa1;
    loadA(0, pa0, pa1);
    splitStore(0, pa0, pa1);
    loadA(1, pa0, pa1);
    __syncthreads();

#pragma unroll
    for (int tau = 0; tau < 4; tau++) {
        int b = tau & 1;
        // ---- MFMA: 4 k-steps x 2 col-tiles x 3 products, A frags from LDS --
        float4v acc[2];
        acc[0] = (float4v){0.f, 0.f, 0.f, 0.f};
        acc[1] = (float4v){0.f, 0.f, 0.f, 0.f};
#pragma unroll
        for (int t = 0; t < 4; t++) {
            int pch = (4 * t + q) ^ sw;
            short8 ahi = L->Ah[b][tx][pch];
            short8 alo = L->Al[b][tx][pch];
#pragma unroll
            for (int c = 0; c < 2; c++) {
                acc[c] = __builtin_amdgcn_mfma_f32_16x16x32_bf16(ahi, wh[c][t], acc[c], 0, 0, 0);
                acc[c] = __builtin_amdgcn_mfma_f32_16x16x32_bf16(ahi, wl[c][t], acc[c], 0, 0, 0);
                acc[c] = __builtin_amdgcn_mfma_f32_16x16x32_bf16(alo, wh[c][t], acc[c], 0, 0, 0);
            }
        }

        // ---- scatter acc to Cs: C[lr = 4q+p][col = 16*(2wv+c)+tx] ----------
#pragma unroll
        for (int c = 0; c < 2; c++) {
            int col = 16 * (2 * wv + c) + tx;
#pragma unroll
            for (int p = 0; p < 4; p++) {
                int lr = 4 * q + p;
                L->Cs[lr * CS_STRIDE + ((col + 4 * lr) & 127)] = acc[c][p];
            }
        }

        // ---- split tile tau+1 into buf b^1; prefetch tile tau+2 ------------
        if (tau < 3) {
            splitStore(b ^ 1, pa0, pa1);
            if (tau < 2) loadA(tau + 2, pa0, pa1);
        }
        __syncthreads();   // Cs ready; A(tau+1) ready

        // ---- epilogue: 16-lane group (wv,q) owns row lr = 4*wv + q ---------
        int lr = 4 * wv + q;
        int row = row0 + tau * 16 + lr;
        if (row < n) {   // uniform within the 16-lane group
            float y[8];
#pragma unroll
            for (int c = 0; c < 8; c++)
                y[c] = L->Cs[lr * CS_STRIDE + ((16 * c + tx + 4 * lr) & 127)];

            float s = 0.f;
#pragma unroll
            for (int c = 0; c < 8; c++) s += y[c] * y[c];
            float yn2 = reduce16(s);
            float sc, xns;
            if (ENCODE) {
                float nn = fmaxf(XN[row], 1e-15f);
                float t = fast_tanh(nn);
                sc = t * rcpf(nn);                  // expmap0 scale
                float pn = fmaxf(t, 1e-15f);
                if (pn > MAXNORM) { sc *= MAXNORM * rcpf(pn); pn = MAXNORM; }  // proj
                xns = pn;
            } else {
                sc = 1.0f;
                xns = fmaxf(XN[row], 1e-15f);
            }
            float mxn2 = sc * sc * yn2;
            float mxn = fmaxf(fsqrtf(mxn2), 1e-15f);
            float arg = (mxn * rcpf(xns)) * fast_atanh(fminf(xns, ART_CLAMP));
            float t = fast_tanh(arg);
            float s2 = (mxn2 == 0.0f) ? 0.0f : (sc * t * rcpf(mxn));  // zero-row guard
            float h[8];
#pragma unroll
            for (int c = 0; c < 8; c++) h[c] = y[c] * s2;
            float rn = fmaxf(t, 1e-15f);   // ||res|| == t analytically
            float hn = rn;
            if (rn > MAXNORM) {
                float f = MAXNORM * rcpf(rn);
#pragma unroll
                for (int c = 0; c < 8; c++) h[c] *= f;
                hn = MAXNORM;
            }
            float x2 = hn * hn;
            float d0 = 0.f;
#pragma unroll
            for (int c = 0; c < 8; c++) d0 += h[c] * hbf[c];
            float xy = reduce16(d0);
            float k1 = 1.0f + 2.0f * xy + hb2;
            float k2 = 1.0f - x2;
            float den = fmaxf(1.0f + 2.0f * xy + x2 * hb2, 1e-15f);
            float rden = rcpf(den);
            float av[8];
            float s3 = 0.f;
#pragma unroll
            for (int c = 0; c < 8; c++) {
                av[c] = (k1 * h[c] + k2 * hbf[c]) * rden;
                s3 += av[c] * av[c];
            }
            float an = fmaxf(fsqrtf(reduce16(s3)), 1e-15f);
            float fproj = 1.0f;
            if (an > MAXNORM) { fproj = MAXNORM * rcpf(an); an = MAXNORM; }
            float lm = fproj * fast_atanh(fminf(an, ART_CLAMP)) * rcpf(an);  // proj+logmap0
            uint16_t* o = XT + (size_t)row * D + tx;
#pragma unroll
            for (int c = 0; c < 8; c++) o[16 * c] = f2bf(av[c] * lm);
        }
        __syncthreads();   // Cs free for next tile's scatter
    }
}

// ---------------- CSR aggregation body (4-deep pipeline + degree-perm) -------
// perm maps slot idx -> node id, sorted by DESCENDING degree. The 4 nodes in
// a wave then have near-equal degree, so the wave-max-degree padded loop
// iterations (~24% at Poisson(16), each issuing real queue-slot-consuming
// gathers) vanish. Per-node math/edge-order unchanged -> output bits
// identical for ANY permutation. perm == nullptr -> identity (fallback).

template <bool STORE_HN>
__device__ __forceinline__ void agg_body(int gbid, int tid,
                                         const uint16_t* __restrict__ XT,
                                         const int* __restrict__ rp,
                                         const int2* __restrict__ sorted,
                                         const int* __restrict__ perm,
                                         float* __restrict__ OUT,
                                         float* __restrict__ HN, int n) {
    int lane = tid & 63;
    int q = lane >> 4;                         // node slot within wave (0..3)
    int tx = lane & 15;                        // 16-B chunk within row
    int idx = gbid * 16 + (tid >> 6) * 4 + q;  // slot id
    bool valid = (idx < n);
    int g = valid ? (perm ? perm[idx] : idx) : (n - 1);   // node id
    uint32_t beg = (uint32_t)rp[g];
    uint32_t end = valid ? (uint32_t)rp[g + 1] : beg;
    uint32_t deg = end - beg;

    // wave-max degree -> uniform trip count (≈ per-node degree after perm)
    int m = (int)deg;
    m = max(m, __shfl_xor(m, 16, 64));
    m = max(m, __shfl_xor(m, 32, 64));
    int ms = __builtin_amdgcn_readfirstlane(m);

    const char* sbase = (const char*)sorted;
    const char* xbase = (const char*)XT;
    uint32_t txoff = (uint32_t)tx * 16u;
    uint32_t jb = beg * 8u;                    // byte cursor into sorted[]
    uint32_t jendb = end * 8u;
    uint32_t jlastb = (jendb > 0u) ? (jendb - 8u) : 0u;  // safe clamp target

    float a[8];
#pragma unroll
    for (int c = 0; c < 8; c++) a[c] = 0.f;

    // prologue: 4 metas in flight
    int2 e0 = *(const int2*)(sbase + min(jb, jlastb));
    int2 e1 = *(const int2*)(sbase + min(jb + 8u, jlastb));
    int2 e2 = *(const int2*)(sbase + min(jb + 16u, jlastb));
    int2 e3 = *(const int2*)(sbase + min(jb + 24u, jlastb));
    for (int i = 0; i < ms; i += 4) {
        int2 f0 = *(const int2*)(sbase + min(jb + 32u, jlastb));
        int2 f1 = *(const int2*)(sbase + min(jb + 40u, jlastb));
        int2 f2 = *(const int2*)(sbase + min(jb + 48u, jlastb));
        int2 f3 = *(const int2*)(sbase + min(jb + 56u, jlastb));
        intv4 u0 = *(const intv4*)(xbase + ((((uint32_t)e0.x) << 8) + txoff));
        intv4 u1 = *(const intv4*)(xbase + ((((uint32_t)e1.x) << 8) + txoff));
        intv4 u2 = *(const intv4*)(xbase + ((((uint32_t)e2.x) << 8) + txoff));
        intv4 u3 = *(const intv4*)(xbase + ((((uint32_t)e3.x) << 8) + txoff));
        float w0 = (jb < jendb) ? __int_as_float(e0.y) : 0.f;
        float w1 = (jb + 8u < jendb) ? __int_as_float(e1.y) : 0.f;
        float w2 = (jb + 16u < jendb) ? __int_as_float(e2.y) : 0.f;
        float w3 = (jb + 24u < jendb) ? __int_as_float(e3.y) : 0.f;
#pragma unroll
        for (int k = 0; k < 4; k++) {
            a[2 * k]     = fmaf(__uint_as_float(((uint32_t)u0[k]) << 16), w0, a[2 * k]);
            a[2 * k + 1] = fmaf(__uint_as_float(((uint32_t)u0[k]) & 0xFFFF0000u), w0, a[2 * k + 1]);
        }
#pragma unroll
        for (int k = 0; k < 4; k++) {
            a[2 * k]     = fmaf(__uint_as_float(((uint32_t)u1[k]) << 16), w1, a[2 * k]);
            a[2 * k + 1] = fmaf(__uint_as_float(((uint32_t)u1[k]) & 0xFFFF0000u), w1, a[2 * k + 1]);
        }
#pragma unroll
        for (int k = 0; k < 4; k++) {
            a[2 * k]     = fmaf(__uint_as_float(((uint32_t)u2[k]) << 16), w2, a[2 * k]);
            a[2 * k + 1] = fmaf(__uint_as_float(((uint32_t)u2[k]) & 0xFFFF0000u), w2, a[2 * k + 1]);
        }
#pragma unroll
        for (int k = 0; k < 4; k++) {
            a[2 * k]     = fmaf(__uint_as_float(((uint32_t)u3[k]) << 16), w3, a[2 * k]);
            a[2 * k + 1] = fmaf(__uint_as_float(((uint32_t)u3[k]) & 0xFFFF0000u), w3, a[2 * k + 1]);
        }
        jb += 32u;
        e0 = f0; e1 = f1; e2 = f2; e3 = f3;
    }

    // ---- stage C inline (per 16-lane group), fast transcendentals ----
    float ss = 0.f;
#pragma unroll
    for (int c = 0; c < 8; c++) ss += a[c] * a[c];
    float nn = fmaxf(fsqrtf(reduce16(ss)), 1e-15f);
    float t = fast_tanh(nn);
    float sc = t * rcpf(nn);                 // expmap0
    float pn = fmaxf(t, 1e-15f);
    if (pn > MAXNORM) { sc *= MAXNORM * rcpf(pn); pn = MAXNORM; }  // proj
    float lm = fast_atanh(fminf(pn, ART_CLAMP)) * rcpf(pn);        // logmap0
    float r[8];
    float ss2 = 0.f;
#pragma unroll
    for (int c = 0; c < 8; c++) {
        r[c] = fmaxf(lm * sc * a[c], 0.f);   // relu in tangent space
        ss2 += r[c] * r[c];
    }
    float rn = fmaxf(fsqrtf(reduce16(ss2)), 1e-15f);
    float t2 = fast_tanh(rn);
    float sc2 = t2 * rcpf(rn);               // expmap0 at c_out
    float on = fmaxf(t2, 1e-15f);
    if (on > MAXNORM) { sc2 *= MAXNORM * rcpf(on); on = MAXNORM; }
    if (valid) {
        float4* o = (float4*)(OUT + (size_t)g * D + tx * 8);
        o[0] = make_float4(r[0] * sc2, r[1] * sc2, r[2] * sc2, r[3] * sc2);
        o[1] = make_float4(r[4] * sc2, r[5] * sc2, r[6] * sc2, r[7] * sc2);
        if (STORE_HN && tx == 0) HN[g] = on;   // next layer's _norm(x)
    }
}

// ---------------- kernels ----------------------------------------------------

// fusedPre: rowNorms | bucketHisto | prepW | bias (all independent)
__global__ __launch_bounds__(256) void fusedPre(
    const float* __restrict__ X, float* __restrict__ XN, int n,
    const int* __restrict__ DST, int* __restrict__ bcnt, int* __restrict__ Hcnt,
    int E, int B, int gH,
    const float* __restrict__ W1, const float* __restrict__ W2,
    uint16_t* __restrict__ Whi1, uint16_t* __restrict__ Wlo1,
    uint16_t* __restrict__ Whi2, uint16_t* __restrict__ Wlo2,
    const float* __restrict__ B1, const float* __restrict__ B2,
    float* __restrict__ HBOUT) {
    __shared__ int cnt[1024];
    int bid = blockIdx.x, tid = threadIdx.x;
    if (bid < NB_ROWN) {
        rowNorms_body(bid, tid, X, XN, n);
    } else if (bid < NB_ROWN + gH) {
        histo_body(bid - NB_ROWN, tid, DST, bcnt, Hcnt, E, B, cnt);
    } else if (bid < NB_ROWN + gH + 64) {
        prepW_body(bid - NB_ROWN - gH, tid, W1, W2, Whi1, Wlo1, Whi2, Wlo2);
    } else {
        bias_body(bid - NB_ROWN - gH - 64, tid, B1, B2, HBOUT);
    }
}

// single block: exclusive scan of bcnt (B <= 1024) -> boff; rp[n]=boff[B]=E
__global__ __launch_bounds__(1024) void bucketScan(const int* __restrict__ bcnt,
                                                   int* __restrict__ boff,
                                                   int* __restrict__ rp_last,
                                                   int B, int E) {
    __shared__ int sd[1024];
    int tid = threadIdx.x;
    int v = (tid < B) ? bcnt[tid] : 0;
    sd[tid] = v;
    __syncthreads();
    for (int off = 1; off < 1024; off <<= 1) {
        int t = (tid >= off) ? sd[tid - off] : 0;
        __syncthreads();
        sd[tid] += t;
        __syncthreads();
    }
    int ex = sd[tid] - v;
    if (tid < B) boff[tid] = ex;
    if (tid == 0) { boff[B] = E; *rp_last = E; }
}

// scanA v2: one block per bucket; PARALLEL prefix over histo-blocks k.
__global__ __launch_bounds__(256) void scanA(const int* __restrict__ boff,
                                             const int* __restrict__ Hcnt,
                                             int* __restrict__ Hbase, int B, int gH) {
    __shared__ int sd[256];
    int b = blockIdx.x;
    int k = threadIdx.x;
    int base0 = boff[b];
    int carry = 0;
    for (int k0 = 0; k0 < gH; k0 += 256) {
        int kk = k0 + k;
        int v = (kk < gH) ? Hcnt[(size_t)kk * B + b] : 0;
        sd[k] = v;
        __syncthreads();
        for (int off = 1; off < 256; off <<= 1) {
            int t = (k >= off) ? sd[k - off] : 0;
            __syncthreads();
            sd[k] += t;
            __syncthreads();
        }
        if (kk < gH) Hbase[(size_t)kk * B + b] = base0 + carry + sd[k] - v;
        carry += sd[255];
        __syncthreads();
    }
}

// fusedBinGemm: binEdges | gemm1 blocks [0, GA)
__global__ __launch_bounds__(256, 3) void fusedBinGemm(
    const int* __restrict__ DST, const int* __restrict__ SRC,
    const float* __restrict__ EW, const int* __restrict__ Hbase,
    int2* __restrict__ binned, int E, int B, int gBin,
    const float* __restrict__ A, const uint16_t* __restrict__ Whi,
    const uint16_t* __restrict__ Wlo, const float* __restrict__ XN,
    const float* __restrict__ HB, uint16_t* __restrict__ XT, int n) {
    __shared__ LdsBG u;
    int bid = blockIdx.x, tid = threadIdx.x;
    if (bid < gBin)
        binEdges_body(bid, tid, DST, SRC, EW, Hbase, binned, E, B, u.b.cnt, u.b.base);
    else
        gemm_body<true>(bid - gBin, 0, tid, A, Whi, Wlo, XN, HB, XT, n, &u.g);
}

// fusedSortGemm: perBucketSort | gemm1 blocks [GA, gG)
__global__ __launch_bounds__(256, 3) void fusedSortGemm(
    int2* __restrict__ binned, const int* __restrict__ boff,
    int* __restrict__ rp, int n, int gSort,
    const float* __restrict__ A, const uint16_t* __restrict__ Whi,
    const uint16_t* __restrict__ Wlo, const float* __restrict__ XN,
    const float* __restrict__ HB, uint16_t* __restrict__ XT, int rowOff) {
    __shared__ LdsSG u;
    int bid = blockIdx.x, tid = threadIdx.x;
    if (bid < gSort)
        sort_body(bid, tid, binned, boff, rp, n, u.s.cnt, u.s.cur, u.s.buf);
    else
        gemm_body<true>(bid - gSort, rowOff, tid, A, Whi, Wlo, XN, HB, XT, n, &u.g);
}

// standalone gemm (layer 2)
template <bool ENCODE>
__global__ __launch_bounds__(256, 3) void gemmM(const float* __restrict__ A,
                                                const uint16_t* __restrict__ Whi,
                                                const uint16_t* __restrict__ Wlo,
                                                const float* __restrict__ XN,
                                                const float* __restrict__ HB,
                                                uint16_t* __restrict__ XT, int n) {
    __shared__ GemmLds L;
    gemm_body<ENCODE>(blockIdx.x, 0, threadIdx.x, A, Whi, Wlo, XN, HB, XT, n, &L);
}

// standalone aggregation (degree-permuted)
template <bool STORE_HN>
__global__ __launch_bounds__(256) void aggC(const uint16_t* __restrict__ XT,
                                            const int* __restrict__ rp,
                                            const int2* __restrict__ sorted,
                                            const int* __restrict__ perm,
                                            float* __restrict__ OUT,
                                            float* __restrict__ HN, int n) {
    agg_body<STORE_HN>(blockIdx.x, threadIdx.x, XT, rp, sorted, perm, OUT, HN, n);
}

// ---------------- degree-sort permutation (256-bin counting sort) ------------
// bin = 255 - min(deg,255): ascending scan => DESCENDING degree order.
// v2 scatter: LDS-staged (one global atomic per (block,bin), not per node --
// round-13's per-node version serialized 100K RMWs over 256 addresses, 282us).
// Any permutation is bit-exact; within-bin order is scheduling-only.

__global__ __launch_bounds__(256) void degHisto(const int* __restrict__ rp,
                                                int* __restrict__ dhist, int n) {
    __shared__ int h[256];
    int tid = threadIdx.x;
    h[tid] = 0;
    __syncthreads();
    int g = blockIdx.x * 256 + tid;
    if (g < n) {
        int d = rp[g + 1] - rp[g];
        atomicAdd(&h[255 - min(d, 255)], 1);
    }
    __syncthreads();
    if (h[tid]) atomicAdd(&dhist[tid], h[tid]);
}

__global__ __launch_bounds__(256) void degScan(const int* __restrict__ dhist,
                                               int* __restrict__ dcur) {
    __shared__ int sd[256];
    int tid = threadIdx.x;
    int v = dhist[tid];
    sd[tid] = v;
    __syncthreads();
    for (int off = 1; off < 256; off <<= 1) {
        int t = (tid >= off) ? sd[tid - off] : 0;
        __syncthreads();
        sd[tid] += t;
        __syncthreads();
    }
    dcur[tid] = sd[tid] - v;   // exclusive
}

__global__ __launch_bounds__(256) void permScatter(const int* __restrict__ rp,
                                                   int* __restrict__ dcur,
                                                   int* __restrict__ perm, int n) {
    __shared__ int cnt[256];   // per-block per-bin count
    __shared__ int base[256];  // reserved global base per bin
    int tid = threadIdx.x;
    cnt[tid] = 0;
    __syncthreads();
    int g = blockIdx.x * 256 + tid;
    int bin = -1, r = 0;
    if (g < n) {
        int d = rp[g + 1] - rp[g];
        bin = 255 - min(d, 255);
        r = atomicAdd(&cnt[bin], 1);     // LDS: rank within (block,bin)
    }
    __syncthreads();
    int c = cnt[tid];
    base[tid] = (c > 0) ? atomicAdd(&dcur[tid], c) : 0;   // 1 global RMW/(blk,bin)
    __syncthreads();
    if (g < n) perm[base[bin] + r] = g;
}

// ---------------- launcher ---------------------------------------------------

extern "C" void kernel_launch(void* const* d_in, const int* in_sizes, int n_in,
                              void* d_out, int out_size, void* d_ws, size_t ws_size,
                              hipStream_t stream) {
    const float* x  = (const float*)d_in[0];
    const int*   ei = (const int*)d_in[1];
    const float* ew = (const float*)d_in[2];
    const float* w1 = (const float*)d_in[3];
    const float* b1 = (const float*)d_in[4];
    const float* w2 = (const float*)d_in[5];
    const float* b2 = (const float*)d_in[6];
    int n = in_sizes[0] / D;
    int E = in_sizes[2];
    int B = (n + BKT_NODES - 1) >> BKT_BITS;    // 782 for n=100000 (<= 1024)

    // workspace layout
    uint16_t* xtb = (uint16_t*)d_ws;               // n*D bf16 (T1 then T2, in place)
    int*   bcnt = (int*)(xtb + (size_t)n * D);     // 1024
    int*   boff = bcnt + 1024;                     // 1025
    int*   gcur = boff + 1025;                     // 1024 (unused, layout keep)
    int*   rp   = gcur + 1024;                     // n+1
    float* xn   = (float*)(rp + n + 1);            // n (X norms, then H norms)
    uint16_t* whi1 = (uint16_t*)(((uintptr_t)(xn + n) + 15) & ~(uintptr_t)15);  // 16B-aligned
    uint16_t* wlo1 = whi1 + 128 * 128;
    uint16_t* whi2 = wlo1 + 128 * 128;
    uint16_t* wlo2 = whi2 + 128 * 128;
    float* hb = (float*)(wlo2 + 128 * 128);        // 2*D
    uintptr_t p = (uintptr_t)(hb + 2 * D);
    int2* binned = (int2*)((p + 15) & ~(uintptr_t)15);  // E pairs (binned, then CSR-sorted)
    float* Hd = (float*)d_out;                     // H1 scratch + final out

    const int* dst = ei;      // edge_index[0] = segment ids (destinations)
    const int* src = ei + E;  // edge_index[1] = gather sources

    const int gE8 = (E + 8191) / 8192;
    int* Hcnt  = (int*)(binned + E);               // gE8 * B
    int* Hbase = Hcnt + (size_t)gE8 * B;           // gE8 * B
    int* dhist = Hbase + (size_t)gE8 * B;          // 256
    int* dcur  = dhist + 256;                      // 256
    int* perm  = dcur + 256;                       // n
    size_t need = (size_t)((char*)(perm + n) - (char*)d_ws);
    const int* permUse = (ws_size >= need) ? perm : nullptr;

    const int gG = (n + 63) / 64;      // gemm blocks (64 rows each, 4 tiles)
    const int GA = min(256, gG);       // gemm1 part A (overlaps binEdges)
    const int GB = gG - GA;            // gemm1 part B (overlaps perBucketSort)
    const int gAgg = (n + 15) / 16;    // 4 nodes per wave, 4 waves per block
    const int gN256 = (n + 255) / 256;

    hipMemsetAsync(bcnt, 0, 1024 * sizeof(int), stream);
    if (permUse) hipMemsetAsync(dhist, 0, 256 * sizeof(int), stream);

    // 1: rowNorms | bucketHisto(+Hcnt) | prepW | bias (independent)
    fusedPre<<<NB_ROWN + gE8 + 64 + 2, 256, 0, stream>>>(
        x, xn, n, dst, bcnt, Hcnt, E, B, gE8,
        w1, w2, whi1, wlo1, whi2, wlo2, b1, b2, hb);

    // 2: bucket scan (tiny)
    bucketScan<<<1, 1024, 0, stream>>>(bcnt, boff, rp + n, B, E);

    // 3: per-(block,bucket) base table -- PARALLEL prefix (one block/bucket)
    scanA<<<B, 256, 0, stream>>>(boff, Hcnt, Hbase, B, gE8);

    // 4: binEdges | gemm1[0, GA)
    fusedBinGemm<<<gE8 + GA, 256, 0, stream>>>(
        dst, src, ew, Hbase, binned, E, B, gE8,
        x, whi1, wlo1, xn, hb, xtb, n);

    // 5: perBucketSort | gemm1[GA, gG)
    fusedSortGemm<<<B + GB, 256, 0, stream>>>(
        binned, boff, rp, n, B,
        x, whi1, wlo1, xn, hb, xtb, GA * 64);

    // 6: degree-sort permutation (needs rp; LDS-staged scatter, ~6us total)
    if (permUse) {
        degHisto<<<gN256, 256, 0, stream>>>(rp, dhist, n);
        degScan<<<1, 256, 0, stream>>>(dhist, dcur);
        permScatter<<<gN256, 256, 0, stream>>>(rp, dcur, perm, n);
    }

    // 7-9: layer-1 aggregation, layer-2 gemm + aggregation (round-10 schedule)
    aggC<true><<<gAgg, 256, 0, stream>>>(xtb, rp, binned, permUse, Hd, xn, n);
    gemmM<false><<<gG, 256, 0, stream>>>(Hd, whi2, wlo2, xn, hb + D, xtb, n);
    aggC<false><<<gAgg, 256, 0, stream>>>(xtb, rp, binned, permUse,
                                          (float*)d_out, nullptr, n);
}

// Round 15
// 376.012 us; speedup vs baseline: 1.7840x; 1.0497x over previous
//
#include <hip/hip_runtime.h>
#include <math.h>
#include <stdint.h>

#define D 128
#define MAXNORM (1.0f - 4e-3f)
#define ART_CLAMP 0.9999999f  /* fp32(1 - 1e-7) */
#define BKT_BITS 7             /* 128 nodes per bucket */
#define BKT_NODES 128
#define BKT_CAP 4096           /* LDS sort capacity; mean deg*128 = 2048, 40 sigma margin */
#define NB_ROWN 1024           /* rowNorms virtual grid (fixed) */

typedef __attribute__((ext_vector_type(8))) short short8;   // 8 bf16 (4 VGPR)
typedef __attribute__((ext_vector_type(4))) float float4v;  // MFMA C/D (4 fp32)
typedef __attribute__((ext_vector_type(4))) int intv4;      // 16B gather load

// butterfly all-reduce: every lane ends with the 64-lane total
__device__ __forceinline__ float waveAllReduce(float v) {
#pragma unroll
    for (int off = 32; off; off >>= 1) v += __shfl_xor(v, off, 64);
    return v;
}

// all-reduce across a 16-lane group (lanes differing in low 4 bits)
__device__ __forceinline__ float reduce16(float v) {
    v += __shfl_xor(v, 8, 64);
    v += __shfl_xor(v, 4, 64);
    v += __shfl_xor(v, 2, 64);
    v += __shfl_xor(v, 1, 64);
    return v;
}

// fp32 -> bf16 bits, round-to-nearest-even
__device__ __forceinline__ uint16_t f2bf(float f) {
    uint32_t u = __float_as_uint(f);
    uint32_t r = u + 0x7FFFu + ((u >> 16) & 1u);
    return (uint16_t)(r >> 16);
}
__device__ __forceinline__ float bf2f(uint16_t b) {
    return __uint_as_float((uint32_t)b << 16);
}

// ---- fast transcendentals (HW v_exp/v_log/v_rcp/v_sqrt, rel err ~1e-7) ----
__device__ __forceinline__ float rcpf(float x) { return __builtin_amdgcn_rcpf(x); }
__device__ __forceinline__ float fsqrtf(float x) { return __builtin_amdgcn_sqrtf(x); }
__device__ __forceinline__ float fast_tanh(float x) {
    float e = __expf(2.0f * x);
    float t = 1.0f - 2.0f * rcpf(e + 1.0f);
    return (x < 1e-4f) ? x : t;
}
__device__ __forceinline__ float fast_atanh(float x) {
    float t = 0.5f * __logf((1.0f + x) * rcpf(1.0f - x));
    return (x < 1e-4f) ? x : t;
}

// ---------------- LDS overlay types for fused kernels ------------------------

#define CS_STRIDE 136   /* fp32 words per LDS C-row: bank rotation, writes 2-way max */

struct GemmLds {
    short8 Ah[2][16][16];            // 8KB  A hi frags, double-buffered
    short8 Al[2][16][16];            // 8KB  A lo frags
    float Cs[16 * CS_STRIDE];        // 8.7KB C redistribution
};
struct BinLds { int cnt[1024]; int base[1024]; };
struct SortLds { int cnt[BKT_NODES]; int cur[BKT_NODES]; int2 buf[BKT_CAP]; };
union LdsBG { GemmLds g; BinLds b; };    // 25.1 KB
union LdsSG { GemmLds g; SortLds s; };   // 33.8 KB

// ---------------- device bodies ----------------------------------------------

__device__ __forceinline__ void rowNorms_body(int bid, int tid,
                                              const float* __restrict__ X,
                                              float* __restrict__ XN, int n) {
    int lane = tid & 63;
    int wv = (bid * 256 + tid) >> 6;
    const int nw = (NB_ROWN * 256) >> 6;
    for (int r = wv; r < n; r += nw) {
        float2 v = *(const float2*)(X + (size_t)r * D + lane * 2);
        float nn = sqrtf(waveAllReduce(v.x * v.x + v.y * v.y));
        if (lane == 0) XN[r] = nn;
    }
}

// histo: per-block counts -> Hcnt (coalesced, no atomics) + global bcnt with
// block-staggered atomics (kills the lockstep per-address contention bursts).
__device__ __forceinline__ void histo_body(int bid, int tid,
                                           const int* __restrict__ DST,
                                           int* __restrict__ bcnt,
                                           int* __restrict__ Hcnt, int E, int B,
                                           int* cnt) {
    for (int i = tid; i < B; i += 256) cnt[i] = 0;
    __syncthreads();
    int start = bid * 8192;
    int endE = min(start + 8192, E);
    for (int e = start + tid; e < endE; e += 256)
        atomicAdd(&cnt[DST[e] >> BKT_BITS], 1);
    __syncthreads();
    int off = (bid * 131) % B;
    for (int i = tid; i < B; i += 256) {
        int j = i + off;
        if (j >= B) j -= B;
        int c = cnt[j];
        Hcnt[bid * B + j] = c;
        if (c) atomicAdd(&bcnt[j], c);
    }
}

__device__ __forceinline__ void prepW_body(int bid, int tid,
                                           const float* __restrict__ W1,
                                           const float* __restrict__ W2,
                                           uint16_t* __restrict__ Whi1,
                                           uint16_t* __restrict__ Wlo1,
                                           uint16_t* __restrict__ Whi2,
                                           uint16_t* __restrict__ Wlo2) {
    int i = bid * 256 + tid;  // 0..16383
    float a1 = W1[i];
    uint16_t h1 = f2bf(a1);
    Whi1[i] = h1;
    Wlo1[i] = f2bf(a1 - bf2f(h1));
    float a2 = W2[i];
    uint16_t h2 = f2bf(a2);
    Whi2[i] = h2;
    Wlo2[i] = f2bf(a2 - bf2f(h2));
}

__device__ __forceinline__ void bias_body(int bid, int tid,
                                          const float* __restrict__ B1,
                                          const float* __restrict__ B2,
                                          float* __restrict__ HBOUT) {
    if (tid >= 64) return;   // one wave; no barriers in this body
    int lane = tid;
    const float* Bp = bid ? B2 : B1;
    float v0 = Bp[lane], v1 = Bp[lane + 64];
    float nn = fmaxf(sqrtf(waveAllReduce(v0 * v0 + v1 * v1)), 1e-15f);
    float t = tanhf(nn);
    float sc = t / nn;
    float pn = fmaxf(t, 1e-15f);
    if (pn > MAXNORM) sc *= MAXNORM / pn;
    HBOUT[bid * D + lane] = v0 * sc;
    HBOUT[bid * D + lane + 64] = v1 * sc;
}

// binEdges: single scatter pass; bases precomputed (Hbase), no global atomics.
__device__ __forceinline__ void binEdges_body(int bid, int tid,
                                              const int* __restrict__ DST,
                                              const int* __restrict__ SRC,
                                              const float* __restrict__ EW,
                                              const int* __restrict__ Hbase,
                                              int2* __restrict__ binned, int E, int B,
                                              int* cnt, int* base) {
    for (int i = tid; i < B; i += 256) {
        base[i] = Hbase[bid * B + i];
        cnt[i] = 0;
    }
    __syncthreads();
    int start = bid * 8192;
    int endE = min(start + 8192, E);
    for (int e = start + tid; e < endE; e += 256) {
        int d = DST[e];
        int bk = d >> BKT_BITS;
        int r = atomicAdd(&cnt[bk], 1);
        binned[base[bk] + r] =
            make_int2(SRC[e] | ((d & (BKT_NODES - 1)) << 24), __float_as_int(EW[e]));
    }
}

__device__ __forceinline__ void sort_body(int b, int tid,
                                          int2* __restrict__ binned,
                                          const int* __restrict__ boff,
                                          int* __restrict__ rp, int n,
                                          int* cnt, int* cur, int2* buf) {
    int beg = boff[b], end = boff[b + 1];
    if (tid < BKT_NODES) cnt[tid] = 0;
    __syncthreads();
    for (int e = beg + tid; e < end; e += 256)
        atomicAdd(&cnt[((uint32_t)binned[e].x) >> 24], 1);
    __syncthreads();
    // exclusive scan over 128 counters (Hillis-Steele, uniform syncs)
    int v = (tid < BKT_NODES) ? cnt[tid] : 0;
    if (tid < BKT_NODES) cur[tid] = v;
    __syncthreads();
    for (int off = 1; off < BKT_NODES; off <<= 1) {
        int t = (tid < BKT_NODES && tid >= off) ? cur[tid - off] : 0;
        __syncthreads();
        if (tid < BKT_NODES) cur[tid] += t;
        __syncthreads();
    }
    if (tid < BKT_NODES) {
        int ex = cur[tid] - v;
        int g = b * BKT_NODES + tid;
        if (g < n) rp[g] = beg + ex;
        cur[tid] = ex;   // scatter cursor
    }
    __syncthreads();
    for (int e = beg + tid; e < end; e += 256) {
        int2 pr = binned[e];
        int dl = ((uint32_t)pr.x) >> 24;
        int pos = atomicAdd(&cur[dl], 1);
        if (pos < BKT_CAP) buf[pos] = make_int2(pr.x & 0x00FFFFFF, pr.y);
    }
    __syncthreads();
    int cnt_tot = end - beg;
    for (int i = tid; i < cnt_tot && i < BKT_CAP; i += 256)
        binned[beg + i] = buf[i];
}

// ---------------- MFMA GEMM body (v4, byte-identical math) -------------------

__device__ __forceinline__ void split8(const float* v, short8* hi, short8* lo) {
    union { uint32_t u[4]; short8 s; } H, L;
#pragma unroll
    for (int i = 0; i < 4; i++) {
        uint16_t h0 = f2bf(v[2 * i]), h1 = f2bf(v[2 * i + 1]);
        uint16_t l0 = f2bf(v[2 * i] - bf2f(h0));
        uint16_t l1 = f2bf(v[2 * i + 1] - bf2f(h1));
        H.u[i] = (uint32_t)h0 | ((uint32_t)h1 << 16);
        L.u[i] = (uint32_t)l0 | ((uint32_t)l1 << 16);
    }
    *hi = H.s;
    *lo = L.s;
}

template <bool ENCODE>
__device__ __forceinline__ void gemm_body(int gbid, int rowOff, int tid,
                                          const float* __restrict__ A,
                                          const uint16_t* __restrict__ Whi,
                                          const uint16_t* __restrict__ Wlo,
                                          const float* __restrict__ XN,
                                          const float* __restrict__ HB,
                                          uint16_t* __restrict__ XT, int n,
                                          GemmLds* L) {
    int lane = tid & 63;
    int wv = tid >> 6;       // wave 0..3
    int tx = lane & 15;      // A row / B col / C col index within tile
    int q = lane >> 4;       // k-group (0..3)
    int sw = tx & 7;
    int row0 = rowOff + gbid * 64;

    // ---- W fragments in registers: ct = 2*wv + c, W row = 16*ct + tx --------
    short8 wh[2][4], wl[2][4];
#pragma unroll
    for (int c = 0; c < 2; c++) {
        int wrow = 16 * (2 * wv + c) + tx;
        const uint16_t* ph = Whi + (size_t)wrow * D + q * 8;
        const uint16_t* pl = Wlo + (size_t)wrow * D + q * 8;
#pragma unroll
        for (int t = 0; t < 4; t++) {
            wh[c][t] = *(const short8*)(ph + t * 32);
            wl[c][t] = *(const short8*)(pl + t * 32);
        }
    }

    // hb fragment (col j = 16c + tx), once per block
    float hbf[8];
#pragma unroll
    for (int c = 0; c < 8; c++) hbf[c] = HB[16 * c + tx];
    float hbsq = 0.f;
#pragma unroll
    for (int c = 0; c < 8; c++) hbsq += hbf[c] * hbf[c];
    float hb2 = reduce16(hbsq);

    // A loader: wave wv owns k-slice [32wv, 32wv+32), lane (tx,q) -> 8 floats
    auto loadA = [&](int tau, float4& v0, float4& v1) {
        int gr = row0 + tau * 16 + tx;
        if (gr >= n) gr = n - 1;  // clamp; epilogue guarded
        const float4* ap = (const float4*)(A + (size_t)gr * D + wv * 32 + q * 8);
        v0 = ap[0];
        v1 = ap[1];
    };
    auto splitStore = [&](int b, float4 v0, float4 v1) {
        float v[8] = {v0.x, v0.y, v0.z, v0.w, v1.x, v1.y, v1.z, v1.w};
        short8 hi, lo;
        split8(v, &hi, &lo);
        int pch = (4 * wv + q) ^ sw;
        L->Ah[b][tx][pch] = hi;
        L->Al[b][tx][pch] = lo;
    };

    // ---- prologue: tile 0 split into buf0; tile 1 loads in flight ----
    float4 pa0, pa1;
    loadA(0, pa0, pa1);
    splitStore(0, pa0, pa1);
    loadA(1, pa0, pa1);
    __syncthreads();

#pragma unroll
    for (int tau = 0; tau < 4; tau++) {
        int b = tau & 1;
        // ---- MFMA: 4 k-steps x 2 col-tiles x 3 products, A frags from LDS --
        float4v acc[2];
        acc[0] = (float4v){0.f, 0.f, 0.f, 0.f};
        acc[1] = (float4v){0.f, 0.f, 0.f, 0.f};
#pragma unroll
        for (int t = 0; t < 4; t++) {
            int pch = (4 * t + q) ^ sw;
            short8 ahi = L->Ah[b][tx][pch];
            short8 alo = L->Al[b][tx][pch];
#pragma unroll
            for (int c = 0; c < 2; c++) {
                acc[c] = __builtin_amdgcn_mfma_f32_16x16x32_bf16(ahi, wh[c][t], acc[c], 0, 0, 0);
                acc[c] = __builtin_amdgcn_mfma_f32_16x16x32_bf16(ahi, wl[c][t], acc[c], 0, 0, 0);
                acc[c] = __builtin_amdgcn_mfma_f32_16x16x32_bf16(alo, wh[c][t], acc[c], 0, 0, 0);
            }
        }

        // ---- scatter acc to Cs: C[lr = 4q+p][col = 16*(2wv+c)+tx] ----------
#pragma unroll
        for (int c = 0; c < 2; c++) {
            int col = 16 * (2 * wv + c) + tx;
#pragma unroll
            for (int p = 0; p < 4; p++) {
                int lr = 4 * q + p;
                L->Cs[lr * CS_STRIDE + ((col + 4 * lr) & 127)] = acc[c][p];
            }
        }

        // ---- split tile tau+1 into buf b^1; prefetch tile tau+2 ------------
        if (tau < 3) {
            splitStore(b ^ 1, pa0, pa1);
            if (tau < 2) loadA(tau + 2, pa0, pa1);
        }
        __syncthreads();   // Cs ready; A(tau+1) ready

        // ---- epilogue: 16-lane group (wv,q) owns row lr = 4*wv + q ---------
        int lr = 4 * wv + q;
        int row = row0 + tau * 16 + lr;
        if (row < n) {   // uniform within the 16-lane group
            float y[8];
#pragma unroll
            for (int c = 0; c < 8; c++)
                y[c] = L->Cs[lr * CS_STRIDE + ((16 * c + tx + 4 * lr) & 127)];

            float s = 0.f;
#pragma unroll
            for (int c = 0; c < 8; c++) s += y[c] * y[c];
            float yn2 = reduce16(s);
            float sc, xns;
            if (ENCODE) {
                float nn = fmaxf(XN[row], 1e-15f);
                float t = fast_tanh(nn);
                sc = t * rcpf(nn);                  // expmap0 scale
                float pn = fmaxf(t, 1e-15f);
                if (pn > MAXNORM) { sc *= MAXNORM * rcpf(pn); pn = MAXNORM; }  // proj
                xns = pn;
            } else {
                sc = 1.0f;
                xns = fmaxf(XN[row], 1e-15f);
            }
            float mxn2 = sc * sc * yn2;
            float mxn = fmaxf(fsqrtf(mxn2), 1e-15f);
            float arg = (mxn * rcpf(xns)) * fast_atanh(fminf(xns, ART_CLAMP));
            float t = fast_tanh(arg);
            float s2 = (mxn2 == 0.0f) ? 0.0f : (sc * t * rcpf(mxn));  // zero-row guard
            float h[8];
#pragma unroll
            for (int c = 0; c < 8; c++) h[c] = y[c] * s2;
            float rn = fmaxf(t, 1e-15f);   // ||res|| == t analytically
            float hn = rn;
            if (rn > MAXNORM) {
                float f = MAXNORM * rcpf(rn);
#pragma unroll
                for (int c = 0; c < 8; c++) h[c] *= f;
                hn = MAXNORM;
            }
            float x2 = hn * hn;
            float d0 = 0.f;
#pragma unroll
            for (int c = 0; c < 8; c++) d0 += h[c] * hbf[c];
            float xy = reduce16(d0);
            float k1 = 1.0f + 2.0f * xy + hb2;
            float k2 = 1.0f - x2;
            float den = fmaxf(1.0f + 2.0f * xy + x2 * hb2, 1e-15f);
            float rden = rcpf(den);
            float av[8];
            float s3 = 0.f;
#pragma unroll
            for (int c = 0; c < 8; c++) {
                av[c] = (k1 * h[c] + k2 * hbf[c]) * rden;
                s3 += av[c] * av[c];
            }
            float an = fmaxf(fsqrtf(reduce16(s3)), 1e-15f);
            float fproj = 1.0f;
            if (an > MAXNORM) { fproj = MAXNORM * rcpf(an); an = MAXNORM; }
            float lm = fproj * fast_atanh(fminf(an, ART_CLAMP)) * rcpf(an);  // proj+logmap0
            uint16_t* o = XT + (size_t)row * D + tx;
#pragma unroll
            for (int c = 0; c < 8; c++) o[16 * c] = f2bf(av[c] * lm);
        }
        __syncthreads();   // Cs free for next tile's scatter
    }
}

// ---------------- kernels ----------------------------------------------------

// fusedPre: rowNorms | bucketHisto | prepW | bias (all independent)
__global__ __launch_bounds__(256) void fusedPre(
    const float* __restrict__ X, float* __restrict__ XN, int n,
    const int* __restrict__ DST, int* __restrict__ bcnt, int* __restrict__ Hcnt,
    int E, int B, int gH,
    const float* __restrict__ W1, const float* __restrict__ W2,
    uint16_t* __restrict__ Whi1, uint16_t* __restrict__ Wlo1,
    uint16_t* __restrict__ Whi2, uint16_t* __restrict__ Wlo2,
    const float* __restrict__ B1, const float* __restrict__ B2,
    float* __restrict__ HBOUT) {
    __shared__ int cnt[1024];
    int bid = blockIdx.x, tid = threadIdx.x;
    if (bid < NB_ROWN) {
        rowNorms_body(bid, tid, X, XN, n);
    } else if (bid < NB_ROWN + gH) {
        histo_body(bid - NB_ROWN, tid, DST, bcnt, Hcnt, E, B, cnt);
    } else if (bid < NB_ROWN + gH + 64) {
        prepW_body(bid - NB_ROWN - gH, tid, W1, W2, Whi1, Wlo1, Whi2, Wlo2);
    } else {
        bias_body(bid - NB_ROWN - gH - 64, tid, B1, B2, HBOUT);
    }
}

// single block: exclusive scan of bcnt (B <= 1024) -> boff; rp[n]=boff[B]=E
__global__ __launch_bounds__(1024) void bucketScan(const int* __restrict__ bcnt,
                                                   int* __restrict__ boff,
                                                   int* __restrict__ rp_last,
                                                   int B, int E) {
    __shared__ int sd[1024];
    int tid = threadIdx.x;
    int v = (tid < B) ? bcnt[tid] : 0;
    sd[tid] = v;
    __syncthreads();
    for (int off = 1; off < 1024; off <<= 1) {
        int t = (tid >= off) ? sd[tid - off] : 0;
        __syncthreads();
        sd[tid] += t;
        __syncthreads();
    }
    int ex = sd[tid] - v;
    if (tid < B) boff[tid] = ex;
    if (tid == 0) { boff[B] = E; *rp_last = E; }
}

// scanA v2: one block per bucket; PARALLEL prefix over histo-blocks k.
__global__ __launch_bounds__(256) void scanA(const int* __restrict__ boff,
                                             const int* __restrict__ Hcnt,
                                             int* __restrict__ Hbase, int B, int gH) {
    __shared__ int sd[256];
    int b = blockIdx.x;
    int k = threadIdx.x;
    int base0 = boff[b];
    int carry = 0;
    for (int k0 = 0; k0 < gH; k0 += 256) {
        int kk = k0 + k;
        int v = (kk < gH) ? Hcnt[(size_t)kk * B + b] : 0;
        sd[k] = v;
        __syncthreads();
        for (int off = 1; off < 256; off <<= 1) {
            int t = (k >= off) ? sd[k - off] : 0;
            __syncthreads();
            sd[k] += t;
            __syncthreads();
        }
        if (kk < gH) Hbase[(size_t)kk * B + b] = base0 + carry + sd[k] - v;
        carry += sd[255];
        __syncthreads();
    }
}

// fusedBinGemm: binEdges | gemm1 blocks [0, GA)
__global__ __launch_bounds__(256, 3) void fusedBinGemm(
    const int* __restrict__ DST, const int* __restrict__ SRC,
    const float* __restrict__ EW, const int* __restrict__ Hbase,
    int2* __restrict__ binned, int E, int B, int gBin,
    const float* __restrict__ A, const uint16_t* __restrict__ Whi,
    const uint16_t* __restrict__ Wlo, const float* __restrict__ XN,
    const float* __restrict__ HB, uint16_t* __restrict__ XT, int n) {
    __shared__ LdsBG u;
    int bid = blockIdx.x, tid = threadIdx.x;
    if (bid < gBin)
        binEdges_body(bid, tid, DST, SRC, EW, Hbase, binned, E, B, u.b.cnt, u.b.base);
    else
        gemm_body<true>(bid - gBin, 0, tid, A, Whi, Wlo, XN, HB, XT, n, &u.g);
}

// fusedSortGemm: perBucketSort | gemm1 blocks [GA, gG)
__global__ __launch_bounds__(256, 3) void fusedSortGemm(
    int2* __restrict__ binned, const int* __restrict__ boff,
    int* __restrict__ rp, int n, int gSort,
    const float* __restrict__ A, const uint16_t* __restrict__ Whi,
    const uint16_t* __restrict__ Wlo, const float* __restrict__ XN,
    const float* __restrict__ HB, uint16_t* __restrict__ XT, int rowOff) {
    __shared__ LdsSG u;
    int bid = blockIdx.x, tid = threadIdx.x;
    if (bid < gSort)
        sort_body(bid, tid, binned, boff, rp, n, u.s.cnt, u.s.cur, u.s.buf);
    else
        gemm_body<true>(bid - gSort, rowOff, tid, A, Whi, Wlo, XN, HB, XT, n, &u.g);
}

// standalone gemm (layer 2)
template <bool ENCODE>
__global__ __launch_bounds__(256, 3) void gemmM(const float* __restrict__ A,
                                                const uint16_t* __restrict__ Whi,
                                                const uint16_t* __restrict__ Wlo,
                                                const float* __restrict__ XN,
                                                const float* __restrict__ HB,
                                                uint16_t* __restrict__ XT, int n) {
    __shared__ GemmLds L;
    gemm_body<ENCODE>(blockIdx.x, 0, threadIdx.x, A, Whi, Wlo, XN, HB, XT, n, &L);
}

// ---------------- CSR aggregation + HypAct (4-deep pipeline, known best) -----

template <bool STORE_HN>
__global__ __launch_bounds__(256) void aggC(const uint16_t* __restrict__ XT,
                                            const int* __restrict__ rp,
                                            const int2* __restrict__ sorted,
                                            float* __restrict__ OUT,
                                            float* __restrict__ HN, int n) {
    int tid = threadIdx.x;
    int lane = tid & 63;
    int q = lane >> 4;                         // node slot within wave (0..3)
    int tx = lane & 15;                        // 16-B chunk within row
    int wv = (blockIdx.x * 256 + tid) >> 6;    // global wave id
    int g = wv * 4 + q;                        // node id
    bool valid = (g < n);
    int gc = valid ? g : (n - 1);
    uint32_t beg = (uint32_t)rp[gc];
    uint32_t end = valid ? (uint32_t)rp[gc + 1] : beg;
    uint32_t deg = end - beg;

    // wave-max degree -> uniform trip count
    int m = (int)deg;
    m = max(m, __shfl_xor(m, 16, 64));
    m = max(m, __shfl_xor(m, 32, 64));
    int ms = __builtin_amdgcn_readfirstlane(m);

    const char* sbase = (const char*)sorted;
    const char* xbase = (const char*)XT;
    uint32_t txoff = (uint32_t)tx * 16u;
    uint32_t jb = beg * 8u;                    // byte cursor into sorted[]
    uint32_t jendb = end * 8u;
    uint32_t jlastb = (jendb > 0u) ? (jendb - 8u) : 0u;  // safe clamp target

    float a[8];
#pragma unroll
    for (int c = 0; c < 8; c++) a[c] = 0.f;

    // prologue: 4 metas in flight
    int2 e0 = *(const int2*)(sbase + min(jb, jlastb));
    int2 e1 = *(const int2*)(sbase + min(jb + 8u, jlastb));
    int2 e2 = *(const int2*)(sbase + min(jb + 16u, jlastb));
    int2 e3 = *(const int2*)(sbase + min(jb + 24u, jlastb));
    for (int i = 0; i < ms; i += 4) {
        int2 f0 = *(const int2*)(sbase + min(jb + 32u, jlastb));
        int2 f1 = *(const int2*)(sbase + min(jb + 40u, jlastb));
        int2 f2 = *(const int2*)(sbase + min(jb + 48u, jlastb));
        int2 f3 = *(const int2*)(sbase + min(jb + 56u, jlastb));
        intv4 u0 = *(const intv4*)(xbase + ((((uint32_t)e0.x) << 8) + txoff));
        intv4 u1 = *(const intv4*)(xbase + ((((uint32_t)e1.x) << 8) + txoff));
        intv4 u2 = *(const intv4*)(xbase + ((((uint32_t)e2.x) << 8) + txoff));
        intv4 u3 = *(const intv4*)(xbase + ((((uint32_t)e3.x) << 8) + txoff));
        float w0 = (jb < jendb) ? __int_as_float(e0.y) : 0.f;
        float w1 = (jb + 8u < jendb) ? __int_as_float(e1.y) : 0.f;
        float w2 = (jb + 16u < jendb) ? __int_as_float(e2.y) : 0.f;
        float w3 = (jb + 24u < jendb) ? __int_as_float(e3.y) : 0.f;
#pragma unroll
        for (int k = 0; k < 4; k++) {
            a[2 * k]     = fmaf(__uint_as_float(((uint32_t)u0[k]) << 16), w0, a[2 * k]);
            a[2 * k + 1] = fmaf(__uint_as_float(((uint32_t)u0[k]) & 0xFFFF0000u), w0, a[2 * k + 1]);
        }
#pragma unroll
        for (int k = 0; k < 4; k++) {
            a[2 * k]     = fmaf(__uint_as_float(((uint32_t)u1[k]) << 16), w1, a[2 * k]);
            a[2 * k + 1] = fmaf(__uint_as_float(((uint32_t)u1[k]) & 0xFFFF0000u), w1, a[2 * k + 1]);
        }
#pragma unroll
        for (int k = 0; k < 4; k++) {
            a[2 * k]     = fmaf(__uint_as_float(((uint32_t)u2[k]) << 16), w2, a[2 * k]);
            a[2 * k + 1] = fmaf(__uint_as_float(((uint32_t)u2[k]) & 0xFFFF0000u), w2, a[2 * k + 1]);
        }
#pragma unroll
        for (int k = 0; k < 4; k++) {
            a[2 * k]     = fmaf(__uint_as_float(((uint32_t)u3[k]) << 16), w3, a[2 * k]);
            a[2 * k + 1] = fmaf(__uint_as_float(((uint32_t)u3[k]) & 0xFFFF0000u), w3, a[2 * k + 1]);
        }
        jb += 32u;
        e0 = f0; e1 = f1; e2 = f2; e3 = f3;
    }

    // ---- stage C inline (per 16-lane group), fast transcendentals ----
    float ss = 0.f;
#pragma unroll
    for (int c = 0; c < 8; c++) ss += a[c] * a[c];
    float nn = fmaxf(fsqrtf(reduce16(ss)), 1e-15f);
    float t = fast_tanh(nn);
    float sc = t * rcpf(nn);                 // expmap0
    float pn = fmaxf(t, 1e-15f);
    if (pn > MAXNORM) { sc *= MAXNORM * rcpf(pn); pn = MAXNORM; }  // proj
    float lm = fast_atanh(fminf(pn, ART_CLAMP)) * rcpf(pn);        // logmap0
    float r[8];
    float ss2 = 0.f;
#pragma unroll
    for (int c = 0; c < 8; c++) {
        r[c] = fmaxf(lm * sc * a[c], 0.f);   // relu in tangent space
        ss2 += r[c] * r[c];
    }
    float rn = fmaxf(fsqrtf(reduce16(ss2)), 1e-15f);
    float t2 = fast_tanh(rn);
    float sc2 = t2 * rcpf(rn);               // expmap0 at c_out
    float on = fmaxf(t2, 1e-15f);
    if (on > MAXNORM) { sc2 *= MAXNORM * rcpf(on); on = MAXNORM; }
    if (valid) {
        float4* o = (float4*)(OUT + (size_t)g * D + tx * 8);
        o[0] = make_float4(r[0] * sc2, r[1] * sc2, r[2] * sc2, r[3] * sc2);
        o[1] = make_float4(r[4] * sc2, r[5] * sc2, r[6] * sc2, r[7] * sc2);
        if (STORE_HN && tx == 0) HN[g] = on;   // next layer's _norm(x)
    }
}

// ---------------- launcher ---------------------------------------------------

extern "C" void kernel_launch(void* const* d_in, const int* in_sizes, int n_in,
                              void* d_out, int out_size, void* d_ws, size_t ws_size,
                              hipStream_t stream) {
    const float* x  = (const float*)d_in[0];
    const int*   ei = (const int*)d_in[1];
    const float* ew = (const float*)d_in[2];
    const float* w1 = (const float*)d_in[3];
    const float* b1 = (const float*)d_in[4];
    const float* w2 = (const float*)d_in[5];
    const float* b2 = (const float*)d_in[6];
    int n = in_sizes[0] / D;
    int E = in_sizes[2];
    int B = (n + BKT_NODES - 1) >> BKT_BITS;    // 782 for n=100000 (<= 1024)

    // workspace layout
    uint16_t* xtb = (uint16_t*)d_ws;               // n*D bf16 (T1 then T2, in place)
    int*   bcnt = (int*)(xtb + (size_t)n * D);     // 1024
    int*   boff = bcnt + 1024;                     // 1025
    int*   gcur = boff + 1025;                     // 1024 (unused, layout keep)
    int*   rp   = gcur + 1024;                     // n+1
    float* xn   = (float*)(rp + n + 1);            // n (X norms, then H norms)
    uint16_t* whi1 = (uint16_t*)(((uintptr_t)(xn + n) + 15) & ~(uintptr_t)15);  // 16B-aligned
    uint16_t* wlo1 = whi1 + 128 * 128;
    uint16_t* whi2 = wlo1 + 128 * 128;
    uint16_t* wlo2 = whi2 + 128 * 128;
    float* hb = (float*)(wlo2 + 128 * 128);        // 2*D
    uintptr_t p = (uintptr_t)(hb + 2 * D);
    int2* binned = (int2*)((p + 15) & ~(uintptr_t)15);  // E pairs (binned, then CSR-sorted)
    float* Hd = (float*)d_out;                     // H1 scratch + final out

    const int* dst = ei;      // edge_index[0] = segment ids (destinations)
    const int* src = ei + E;  // edge_index[1] = gather sources

    const int gE8 = (E + 8191) / 8192;
    int* Hcnt  = (int*)(binned + E);               // gE8 * B
    int* Hbase = Hcnt + (size_t)gE8 * B;           // gE8 * B

    const int gG = (n + 63) / 64;      // gemm blocks (64 rows each, 4 tiles)
    const int GA = min(256, gG);       // gemm1 part A (overlaps binEdges)
    const int GB = gG - GA;            // gemm1 part B (overlaps perBucketSort)
    const int gAgg = (n + 15) / 16;    // 4 nodes per wave, 4 waves per block

    hipMemsetAsync(bcnt, 0, 1024 * sizeof(int), stream);

    // 1: rowNorms | bucketHisto(+Hcnt) | prepW | bias (independent)
    fusedPre<<<NB_ROWN + gE8 + 64 + 2, 256, 0, stream>>>(
        x, xn, n, dst, bcnt, Hcnt, E, B, gE8,
        w1, w2, whi1, wlo1, whi2, wlo2, b1, b2, hb);

    // 2: bucket scan (tiny)
    bucketScan<<<1, 1024, 0, stream>>>(bcnt, boff, rp + n, B, E);

    // 3: per-(block,bucket) base table -- PARALLEL prefix (one block/bucket)
    scanA<<<B, 256, 0, stream>>>(boff, Hcnt, Hbase, B, gE8);

    // 4: binEdges | gemm1[0, GA)
    fusedBinGemm<<<gE8 + GA, 256, 0, stream>>>(
        dst, src, ew, Hbase, binned, E, B, gE8,
        x, whi1, wlo1, xn, hb, xtb, n);

    // 5: perBucketSort | gemm1[GA, gG)
    fusedSortGemm<<<B + GB, 256, 0, stream>>>(
        binned, boff, rp, n, B,
        x, whi1, wlo1, xn, hb, xtb, GA * 64);

    // 6-8: layer-1 aggregation, layer-2 gemm + aggregation
    aggC<true><<<gAgg, 256, 0, stream>>>(xtb, rp, binned, Hd, xn, n);
    gemmM<false><<<gG, 256, 0, stream>>>(Hd, whi2, wlo2, xn, hb + D, xtb, n);
    aggC<false><<<gAgg, 256, 0, stream>>>(xtb, rp, binned, (float*)d_out, nullptr, n);
}